// Round 1
// baseline (2220.817 us; speedup 1.0000x reference)
//
#include <hip/hip_runtime.h>
#include <math.h>

typedef unsigned short ushort_t;
typedef unsigned int uint_t;
typedef __attribute__((ext_vector_type(8))) short bf16x8;
typedef __attribute__((ext_vector_type(4))) float f32x4;

// ---------- bf16 helpers ----------
__device__ inline ushort_t f2bf(float f) {
    union { float f; uint_t u; } x; x.f = f;
    uint_t r = x.u + 0x7fffu + ((x.u >> 16) & 1u);
    return (ushort_t)(r >> 16);
}
__device__ inline float bf2f(ushort_t h) {
    union { uint_t u; float f; } x; x.u = ((uint_t)h) << 16;
    return x.f;
}
__device__ inline float bflo(uint_t u) {
    union { uint_t u; float f; } x; x.u = u << 16; return x.f;
}
__device__ inline float bfhi(uint_t u) {
    union { uint_t u; float f; } x; x.u = u & 0xffff0000u; return x.f;
}

// ---------- generic 3x3 conv (pad=1), 8 output channels per thread ----------
__global__ void conv3x3_k(const float* __restrict__ in, const float* __restrict__ wgt,
                          const float* __restrict__ bias, float* __restrict__ out,
                          int Cin, int H, int W, int relu)
{
    int p = blockIdx.x * 256 + threadIdx.x;
    int HW = H * W;
    if (p >= HW) return;
    int co0 = blockIdx.y * 8;
    int y = p / W, x = p - y * W;
    float acc0 = bias[co0+0], acc1 = bias[co0+1], acc2 = bias[co0+2], acc3 = bias[co0+3];
    float acc4 = bias[co0+4], acc5 = bias[co0+5], acc6 = bias[co0+6], acc7 = bias[co0+7];
    bool ym = y > 0, yp = y < H-1, xm = x > 0, xp = x < W-1;
    for (int ci = 0; ci < Cin; ++ci) {
        const float* ip = in + (size_t)ci * HW + p;
        float v0 = (ym && xm) ? ip[-W-1] : 0.f;
        float v1 = (ym)       ? ip[-W]   : 0.f;
        float v2 = (ym && xp) ? ip[-W+1] : 0.f;
        float v3 = (xm)       ? ip[-1]   : 0.f;
        float v4 =              ip[0];
        float v5 = (xp)       ? ip[1]    : 0.f;
        float v6 = (yp && xm) ? ip[W-1]  : 0.f;
        float v7 = (yp)       ? ip[W]    : 0.f;
        float v8 = (yp && xp) ? ip[W+1]  : 0.f;
        const float* wp = wgt + ((size_t)co0 * Cin + ci) * 9;
        size_t ws = (size_t)Cin * 9;
#define CACC(q, a) { const float* wq = wp + q * ws; \
        a += wq[0]*v0 + wq[1]*v1 + wq[2]*v2 + wq[3]*v3 + wq[4]*v4 \
           + wq[5]*v5 + wq[6]*v6 + wq[7]*v7 + wq[8]*v8; }
        CACC(0, acc0) CACC(1, acc1) CACC(2, acc2) CACC(3, acc3)
        CACC(4, acc4) CACC(5, acc5) CACC(6, acc6) CACC(7, acc7)
#undef CACC
    }
#define CW(q, a) { float r = a; if (relu) r = fmaxf(r, 0.f); out[(size_t)(co0+q)*HW + p] = r; }
    CW(0, acc0) CW(1, acc1) CW(2, acc2) CW(3, acc3)
    CW(4, acc4) CW(5, acc5) CW(6, acc6) CW(7, acc7)
#undef CW
}

// ---------- 2x2 maxpool ----------
__global__ void maxpool_k(const float* __restrict__ in, float* __restrict__ out,
                          int C, int H, int W)
{
    int Ho = H >> 1, Wo = W >> 1;
    int idx = blockIdx.x * 256 + threadIdx.x;
    int total = C * Ho * Wo;
    if (idx >= total) return;
    int x = idx % Wo;
    int y = (idx / Wo) % Ho;
    int c = idx / (Wo * Ho);
    const float* ip = in + ((size_t)c * H + 2*y) * W + 2*x;
    out[idx] = fmaxf(fmaxf(ip[0], ip[1]), fmaxf(ip[W], ip[W+1]));
}

// ---------- bicubic upsample (align_corners=True), PyTorch A=-0.75 ----------
__device__ inline void cubw(float t, float* w) {
    float x0 = 1.f + t, x2 = 1.f - t, x3 = 2.f - t;
    w[0] = ((-0.75f*x0 + 3.75f)*x0 - 6.f)*x0 + 3.f;
    w[1] = (1.25f*t - 2.25f)*t*t + 1.f;
    w[2] = (1.25f*x2 - 2.25f)*x2*x2 + 1.f;
    w[3] = ((-0.75f*x3 + 3.75f)*x3 - 6.f)*x3 + 3.f;
}
__global__ void bicubic_k(const float* __restrict__ in, float* __restrict__ out,
                          int C, int Hin, int Win, int Hout, int Wout)
{
    int idx = blockIdx.x * 256 + threadIdx.x;
    int total = C * Hout * Wout;
    if (idx >= total) return;
    int X = idx % Wout;
    int Y = (idx / Wout) % Hout;
    int c = idx / (Wout * Hout);
    float sy = (float)Y * (float)(Hin - 1) / (float)(Hout - 1);
    float sx = (float)X * (float)(Win - 1) / (float)(Wout - 1);
    int fy = (int)floorf(sy), fx = (int)floorf(sx);
    float ty = sy - (float)fy, tx = sx - (float)fx;
    float wy[4], wx[4];
    cubw(ty, wy); cubw(tx, wx);
    const float* ip = in + (size_t)c * Hin * Win;
    float acc = 0.f;
#pragma unroll
    for (int i = 0; i < 4; ++i) {
        int yy = min(max(fy - 1 + i, 0), Hin - 1);
        float ra = 0.f;
#pragma unroll
        for (int j = 0; j < 4; ++j) {
            int xx = min(max(fx - 1 + j, 0), Win - 1);
            ra += wx[j] * ip[yy * Win + xx];
        }
        acc += wy[i] * ra;
    }
    out[idx] = acc;
}

// ---------- per-pixel inverse L2 norm over 320 channels ----------
__global__ void norms_k(const float* __restrict__ F, float* __restrict__ inv)
{
    int p = blockIdx.x * 256 + threadIdx.x; // < 16384
    float ss = 0.f;
    for (int c = 0; c < 320; ++c) {
        float v = F[(size_t)c * 16384 + p];
        ss += v * v;
    }
    inv[p] = 1.f / (1e-8f + sqrtf(ss));
}

// ---------- transpose [320][16384] -> [16384][320] with per-pixel scale, bf16 out ----------
__global__ void transpose_norm_k(const float* __restrict__ F, const float* __restrict__ inv,
                                 ushort_t* __restrict__ T)
{
    __shared__ float tile[64][65];
    int p0 = blockIdx.x * 64;
    int c0 = blockIdx.y * 64;
    int tid = threadIdx.x;
    int tx = tid & 63;
    int ty = tid >> 6;
#pragma unroll
    for (int i = 0; i < 16; ++i) {
        int cl = ty + i * 4;
        tile[cl][tx] = F[(size_t)(c0 + cl) * 16384 + p0 + tx];
    }
    __syncthreads();
#pragma unroll
    for (int i = 0; i < 16; ++i) {
        int pl = ty + i * 4;
        int p = p0 + pl;
        float v = tile[tx][pl] * inv[p];
        T[(size_t)p * 320 + c0 + tx] = f2bf(v);
    }
}

// ---------- 2x2 mean pool on [16384][320] bf16 -> [4096][320] bf16 ----------
__global__ void pool_ref_k(const ushort_t* __restrict__ T, ushort_t* __restrict__ A)
{
    int idx = blockIdx.x * 256 + threadIdx.x;
    if (idx >= 4096 * 320) return;
    int c = idx % 320;
    int m = idx / 320;
    int y = m >> 6, x = m & 63;
    size_t p00 = ((size_t)(2*y) * 128 + 2*x) * 320 + c;
    float s = bf2f(T[p00]) + bf2f(T[p00 + 320]) + bf2f(T[p00 + 128*320]) + bf2f(T[p00 + 128*320 + 320]);
    A[idx] = f2bf(0.25f * s);
}

// ---------- correlation GEMM: A[4096][320] x B[16384][320]^T -> dist bf16 [4096][16384] ----------
__global__ __launch_bounds__(256) void gemm_corr_k(
    const ushort_t* __restrict__ A, const ushort_t* __restrict__ B, ushort_t* __restrict__ D)
{
    __shared__ ushort_t lA[128 * 32];
    __shared__ ushort_t lB[128 * 32];
    const int tid = threadIdx.x;
    const int lane = tid & 63;
    const int wid = tid >> 6;
    const int wr = wid >> 1, wc = wid & 1;
    const int m0 = blockIdx.y * 128, n0 = blockIdx.x * 128;
    const int rS = tid >> 2;          // 0..63
    const int cS = (tid & 3) << 3;    // 0,8,16,24
    const int fr = lane & 15;
    const int fo = (lane >> 4) << 3;  // 0,8,16,24

    f32x4 zero = {0.f, 0.f, 0.f, 0.f};
    f32x4 acc[4][4];
#pragma unroll
    for (int i = 0; i < 4; ++i)
#pragma unroll
        for (int j = 0; j < 4; ++j) acc[i][j] = zero;

    for (int k0 = 0; k0 < 320; k0 += 32) {
        uint4 a0 = *(const uint4*)(A + (size_t)(m0 + rS) * 320 + k0 + cS);
        uint4 a1 = *(const uint4*)(A + (size_t)(m0 + 64 + rS) * 320 + k0 + cS);
        uint4 b0 = *(const uint4*)(B + (size_t)(n0 + rS) * 320 + k0 + cS);
        uint4 b1 = *(const uint4*)(B + (size_t)(n0 + 64 + rS) * 320 + k0 + cS);
        __syncthreads();
        *(uint4*)&lA[rS * 32 + cS] = a0;
        *(uint4*)&lA[(64 + rS) * 32 + cS] = a1;
        *(uint4*)&lB[rS * 32 + cS] = b0;
        *(uint4*)&lB[(64 + rS) * 32 + cS] = b1;
        __syncthreads();
        bf16x8 af[4], bfr[4];
#pragma unroll
        for (int mi = 0; mi < 4; ++mi)
            af[mi] = *(const bf16x8*)&lA[(wr * 64 + mi * 16 + fr) * 32 + fo];
#pragma unroll
        for (int ni = 0; ni < 4; ++ni)
            bfr[ni] = *(const bf16x8*)&lB[(wc * 64 + ni * 16 + fr) * 32 + fo];
#pragma unroll
        for (int mi = 0; mi < 4; ++mi)
#pragma unroll
            for (int ni = 0; ni < 4; ++ni)
                acc[mi][ni] = __builtin_amdgcn_mfma_f32_16x16x32_bf16(af[mi], bfr[ni], acc[mi][ni], 0, 0, 0);
    }
    const float s = 1.0f / 320.0f;
#pragma unroll
    for (int mi = 0; mi < 4; ++mi) {
#pragma unroll
        for (int ni = 0; ni < 4; ++ni) {
            int grow0 = m0 + wr * 64 + mi * 16 + ((lane >> 4) << 2);
            int gcol = n0 + wc * 64 + ni * 16 + (lane & 15);
#pragma unroll
            for (int r = 0; r < 4; ++r)
                D[(size_t)(grow0 + r) * 16384 + gcol] = f2bf(acc[mi][ni][r] * s);
        }
    }
}

// ---------- column sums of exp(cr*d): stage 1 (partial over 512-row chunks) ----------
__global__ void col_partial_k(const ushort_t* __restrict__ Dist, const float* __restrict__ coefr,
                              float* __restrict__ psum)
{
    int chunk = blockIdx.y;                      // 0..7
    int jj = blockIdx.x * 256 + threadIdx.x;     // 0..8191
    float cr = coefr[0];
    int j = jj * 2;
    const ushort_t* cp = Dist + j;
    float s0 = 0.f, s1 = 0.f;
    int r0 = chunk * 512;
    for (int m = 0; m < 512; ++m) {
        uint_t u = *(const uint_t*)(cp + (size_t)(r0 + m) * 16384);
        s0 += expf(cr * bflo(u));
        s1 += expf(cr * bfhi(u));
    }
    psum[(size_t)chunk * 16384 + j] = s0;
    psum[(size_t)chunk * 16384 + j + 1] = s1;
}
__global__ void col_final_k(const float* __restrict__ psum, float* __restrict__ csum)
{
    int j = blockIdx.x * 256 + threadIdx.x;
    float s = 0.f;
#pragma unroll
    for (int k = 0; k < 8; ++k) s += psum[(size_t)k * 16384 + j];
    csum[j] = s;
}

// ---------- per-row: sum of exp(ct*d), then conf + top-5 (one wave per row) ----------
#define INS5(w_) { float w = (w_); float mx; \
    mx = fmaxf(w, t0); w = fminf(w, t0); t0 = mx; \
    mx = fmaxf(w, t1); w = fminf(w, t1); t1 = mx; \
    mx = fmaxf(w, t2); w = fminf(w, t2); t2 = mx; \
    mx = fmaxf(w, t3); w = fminf(w, t3); t3 = mx; \
    t4 = fmaxf(w, t4); }

__global__ __launch_bounds__(256) void row_topk_k(
    const ushort_t* __restrict__ Dist, const float* __restrict__ csum,
    const float* __restrict__ coefr, const float* __restrict__ coeft,
    float* __restrict__ conf5)
{
    int wid = threadIdx.x >> 6, lane = threadIdx.x & 63;
    int row = blockIdx.x * 4 + wid;
    float cr = coefr[0], ct = coeft[0];
    const ushort_t* rp = Dist + (size_t)row * 16384;

    // pass 1: row sum of exp(ct*d)
    float s = 0.f;
    for (int i = 0; i < 32; ++i) {
        int col = (i * 64 + lane) * 8;
        uint4 u = *(const uint4*)(rp + col);
        s += expf(ct * bflo(u.x)) + expf(ct * bfhi(u.x));
        s += expf(ct * bflo(u.y)) + expf(ct * bfhi(u.y));
        s += expf(ct * bflo(u.z)) + expf(ct * bfhi(u.z));
        s += expf(ct * bflo(u.w)) + expf(ct * bfhi(u.w));
    }
#pragma unroll
    for (int off = 32; off > 0; off >>= 1) s += __shfl_xor(s, off);
    float rs = s;

    // pass 2: conf = exp(0.5*(cr+ct)*d) / sqrt(csum[j]*rs); keep top-5
    float hc = 0.5f * (cr + ct);
    float t0 = -1e30f, t1 = -1e30f, t2 = -1e30f, t3 = -1e30f, t4 = -1e30f;
    for (int i = 0; i < 32; ++i) {
        int col = (i * 64 + lane) * 8;
        uint4 u = *(const uint4*)(rp + col);
        float d0 = bflo(u.x), d1 = bfhi(u.x), d2 = bflo(u.y), d3 = bfhi(u.y);
        float d4 = bflo(u.z), d5 = bfhi(u.z), d6 = bflo(u.w), d7 = bfhi(u.w);
        INS5(expf(hc * d0) / sqrtf(csum[col+0] * rs));
        INS5(expf(hc * d1) / sqrtf(csum[col+1] * rs));
        INS5(expf(hc * d2) / sqrtf(csum[col+2] * rs));
        INS5(expf(hc * d3) / sqrtf(csum[col+3] * rs));
        INS5(expf(hc * d4) / sqrtf(csum[col+4] * rs));
        INS5(expf(hc * d5) / sqrtf(csum[col+5] * rs));
        INS5(expf(hc * d6) / sqrtf(csum[col+6] * rs));
        INS5(expf(hc * d7) / sqrtf(csum[col+7] * rs));
    }
    // merge sorted-5 lists across lanes
#pragma unroll
    for (int off = 1; off < 64; off <<= 1) {
        float o0 = __shfl_xor(t0, off), o1 = __shfl_xor(t1, off), o2 = __shfl_xor(t2, off);
        float o3 = __shfl_xor(t3, off), o4 = __shfl_xor(t4, off);
        INS5(o0); INS5(o1); INS5(o2); INS5(o3); INS5(o4);
    }
    if (lane == 0) {
        conf5[0 * 4096 + row] = t0;
        conf5[1 * 4096 + row] = t1;
        conf5[2 * 4096 + row] = t2;
        conf5[3 * 4096 + row] = t3;
        conf5[4 * 4096 + row] = t4;
    }
}

// ---------- 1x1 conv, Cin->1 ----------
__global__ void conv1x1_k(const float* __restrict__ in, const float* __restrict__ w,
                          const float* __restrict__ b, float* __restrict__ out, int Cin, int HW)
{
    int p = blockIdx.x * 256 + threadIdx.x;
    if (p >= HW) return;
    float a = b[0];
    for (int c = 0; c < Cin; ++c) a += w[c] * in[(size_t)c * HW + p];
    out[p] = a;
}

// ---------- host ----------
extern "C" void kernel_launch(void* const* d_in, const int* in_sizes, int n_in,
                              void* d_out, int out_size, void* d_ws, size_t ws_size,
                              hipStream_t stream)
{
    const float* x_ref = (const float*)d_in[0];
    const float* x_tem = (const float*)d_in[1];
    const float* w0  = (const float*)d_in[2];   const float* b0  = (const float*)d_in[3];
    const float* w2  = (const float*)d_in[4];   const float* b2  = (const float*)d_in[5];
    const float* w5  = (const float*)d_in[6];   const float* b5  = (const float*)d_in[7];
    const float* w7  = (const float*)d_in[8];   const float* b7  = (const float*)d_in[9];
    const float* w10 = (const float*)d_in[10];  const float* b10 = (const float*)d_in[11];
    const float* w12 = (const float*)d_in[12];  const float* b12 = (const float*)d_in[13];
    const float* w14 = (const float*)d_in[14];  const float* b14 = (const float*)d_in[15];
    const float* coefr = (const float*)d_in[16];
    const float* coeft = (const float*)d_in[17];
    const float* fw1 = (const float*)d_in[18];  const float* fb1 = (const float*)d_in[19];
    const float* fw2 = (const float*)d_in[20];  const float* fb2 = (const float*)d_in[21];
    const float* fw3 = (const float*)d_in[22];  const float* fb3 = (const float*)d_in[23];
    float* out = (float*)d_out;

    // workspace bump allocator (256B aligned)
    char* wsp = (char*)d_ws;
    auto alloc = [&](size_t bytes) { char* p = wsp; wsp += (bytes + 255) & ~(size_t)255; return p; };
    float*    F     = (float*)alloc(320 * 16384 * 4);   // feature map [320][128][128]
    float*    tmp1  = (float*)alloc(64 * 16384 * 4);
    float*    tmp2  = (float*)alloc(64 * 16384 * 4);
    float*    inv   = (float*)alloc(16384 * 4);
    ushort_t* Tr    = (ushort_t*)alloc((size_t)16384 * 320 * 2); // ref normalized transposed
    ushort_t* Abuf  = (ushort_t*)alloc((size_t)4096 * 320 * 2);  // pooled ref
    ushort_t* Bbuf  = (ushort_t*)alloc((size_t)16384 * 320 * 2); // tem normalized transposed
    ushort_t* dist  = (ushort_t*)alloc((size_t)4096 * 16384 * 2);
    float*    psum  = (float*)alloc(8 * 16384 * 4);
    float*    csum  = (float*)alloc(16384 * 4);
    float*    conf5 = (float*)alloc(5 * 4096 * 4);
    float*    h1    = (float*)alloc(8 * 4096 * 4);
    float*    h2    = (float*)alloc(8 * 4096 * 4);
    float*    out64 = (float*)alloc(4096 * 4);
    (void)ws_size; (void)n_in; (void)in_sizes; (void)out_size;

    auto features = [&](const float* x, ushort_t* Tout) {
        // conv0 3->64 @128^2 (into F channels 0..63), relu
        conv3x3_k<<<dim3(64, 8), 256, 0, stream>>>(x, w0, b0, F, 3, 128, 128, 1);
        // conv2 64->64 @128^2, relu
        conv3x3_k<<<dim3(64, 8), 256, 0, stream>>>(F, w2, b2, tmp1, 64, 128, 128, 1);
        // pool -> 64 @64^2
        maxpool_k<<<(64 * 64 * 64) / 256, 256, 0, stream>>>(tmp1, tmp2, 64, 128, 128);
        // conv5 64->128 @64^2
        conv3x3_k<<<dim3(16, 16), 256, 0, stream>>>(tmp2, w5, b5, tmp1, 64, 64, 64, 1);
        // conv7 128->128 @64^2
        conv3x3_k<<<dim3(16, 16), 256, 0, stream>>>(tmp1, w7, b7, tmp2, 128, 64, 64, 1);
        // pool -> 128 @32^2
        maxpool_k<<<(128 * 32 * 32) / 256, 256, 0, stream>>>(tmp2, tmp1, 128, 64, 64);
        // conv10 128->256 @32^2
        conv3x3_k<<<dim3(4, 32), 256, 0, stream>>>(tmp1, w10, b10, tmp2, 128, 32, 32, 1);
        // conv12 256->256 @32^2
        conv3x3_k<<<dim3(4, 32), 256, 0, stream>>>(tmp2, w12, b12, tmp1, 256, 32, 32, 1);
        // conv14 256->256 @32^2
        conv3x3_k<<<dim3(4, 32), 256, 0, stream>>>(tmp1, w14, b14, tmp2, 256, 32, 32, 1);
        // bicubic 32->128 into F channels 64..319
        bicubic_k<<<(256 * 16384) / 256, 256, 0, stream>>>(tmp2, F + (size_t)64 * 16384, 256, 32, 32, 128, 128);
        // per-pixel inverse norm over 320 channels
        norms_k<<<64, 256, 0, stream>>>(F, inv);
        // normalized transpose -> bf16 [16384][320]
        transpose_norm_k<<<dim3(256, 5), 256, 0, stream>>>(F, inv, Tout);
    };

    features(x_ref, Tr);
    pool_ref_k<<<(4096 * 320 + 255) / 256, 256, 0, stream>>>(Tr, Abuf);
    features(x_tem, Bbuf);

    // correlation GEMM -> dist bf16 [4096][16384], scaled 1/320
    gemm_corr_k<<<dim3(128, 32), 256, 0, stream>>>(Abuf, Bbuf, dist);

    // column sums of exp(cr*d)
    col_partial_k<<<dim3(32, 8), 256, 0, stream>>>(dist, coefr, psum);
    col_final_k<<<64, 256, 0, stream>>>(psum, csum);

    // fused row sums + confidence + top-5
    row_topk_k<<<1024, 256, 0, stream>>>(dist, csum, coefr, coeft, conf5);

    // head: conv 5->8 relu, conv 8->8 relu, conv1x1 8->1
    conv3x3_k<<<dim3(16, 1), 256, 0, stream>>>(conf5, fw1, fb1, h1, 5, 64, 64, 1);
    conv3x3_k<<<dim3(16, 1), 256, 0, stream>>>(h1, fw2, fb2, h2, 8, 64, 64, 1);
    conv1x1_k<<<16, 256, 0, stream>>>(h2, fw3, fb3, out64, 8, 4096);

    // final bicubic 64->128 -> d_out
    bicubic_k<<<64, 256, 0, stream>>>(out64, out, 1, 64, 64, 128, 128);
}

// Round 2
// 639.316 us; speedup vs baseline: 3.4737x; 3.4737x over previous
//
#include <hip/hip_runtime.h>
#include <math.h>

typedef unsigned short ushort_t;
typedef unsigned int uint_t;
typedef __attribute__((ext_vector_type(8))) short bf16x8;
typedef __attribute__((ext_vector_type(4))) float f32x4;

// ---------- bf16 helpers ----------
__device__ inline ushort_t f2bf(float f) {
    union { float f; uint_t u; } x; x.f = f;
    uint_t r = x.u + 0x7fffu + ((x.u >> 16) & 1u);
    return (ushort_t)(r >> 16);
}
__device__ inline float bf2f(ushort_t h) {
    union { uint_t u; float f; } x; x.u = ((uint_t)h) << 16;
    return x.f;
}
__device__ inline float bflo(uint_t u) {
    union { uint_t u; float f; } x; x.u = u << 16; return x.f;
}
__device__ inline float bfhi(uint_t u) {
    union { uint_t u; float f; } x; x.u = u & 0xffff0000u; return x.f;
}

// ---------- weight transform: OIHW fp32 -> [tap][co][ci] bf16 ----------
__global__ void wtrans_k(const float* __restrict__ w, ushort_t* __restrict__ wT, int CO, int CI)
{
    int idx = blockIdx.x * 256 + threadIdx.x;
    if (idx >= CO * CI * 9) return;
    int tap = idx % 9;
    int rem = idx / 9;
    int ci = rem % CI;
    int co = rem / CI;
    wT[((size_t)tap * CO + co) * CI + ci] = f2bf(w[idx]);
}

// ---------- conv0: 3->64 @128x128, NCHW fp32 in, NHWC bf16 out (into F cols 0..63) ----------
__global__ __launch_bounds__(256) void conv0_k(const float* __restrict__ x, const float* __restrict__ w,
                                               const float* __restrict__ b, ushort_t* __restrict__ F)
{
    int co = threadIdx.x & 63;
    int p = blockIdx.x * 4 + (threadIdx.x >> 6);
    int y = p >> 7, xx = p & 127;
    float acc = b[co];
#pragma unroll
    for (int ci = 0; ci < 3; ++ci) {
#pragma unroll
        for (int t = 0; t < 9; ++t) {
            int dy = t / 3 - 1, dx = t % 3 - 1;
            int yy = y + dy, xc = xx + dx;
            if ((unsigned)yy < 128u && (unsigned)xc < 128u) {
                acc += x[ci * 16384 + yy * 128 + xc] * w[co * 27 + ci * 9 + t];
            }
        }
    }
    F[(size_t)p * 320 + co] = f2bf(fmaxf(acc, 0.f));
}

// ---------- implicit-GEMM MFMA conv 3x3 pad=1: NHWC bf16, relu ----------
// in rows [H*W][ldin] starting at col inoff; wT [9][CO][CI]; out rows [H*W][ldout] at col outoff
template<int CI>
__global__ __launch_bounds__(256) void conv_mfma_k(
    const ushort_t* __restrict__ in, int ldin, int inoff,
    const ushort_t* __restrict__ wT, const float* __restrict__ bias,
    ushort_t* __restrict__ out, int ldout, int outoff,
    int H, int W, int CO)
{
    const int tid = threadIdx.x;
    const int lane = tid & 63, wid = tid >> 6;
    const int wr = wid >> 1, wc = wid & 1;
    const int m0 = blockIdx.x * 64;
    const int n0 = blockIdx.y * 64;
    const int fr = lane & 15;
    const int fo = (lane >> 4) << 3;

    int py[2], px[2];
    size_t abase[2];
    unsigned vmask[2];
#pragma unroll
    for (int mi = 0; mi < 2; ++mi) {
        int p = m0 + wr * 32 + mi * 16 + fr;
        int y = p / W, x = p % W;
        py[mi] = y; px[mi] = x;
        abase[mi] = (size_t)p * ldin + inoff + fo;
        unsigned vm = 0;
#pragma unroll
        for (int t = 0; t < 9; ++t) {
            int dy = t / 3 - 1, dx = t % 3 - 1;
            if ((unsigned)(y + dy) < (unsigned)H && (unsigned)(x + dx) < (unsigned)W) vm |= 1u << t;
        }
        vmask[mi] = vm;
    }

    f32x4 zero = {0.f, 0.f, 0.f, 0.f};
    f32x4 acc[2][2] = {{zero, zero}, {zero, zero}};
    const bf16x8 zz = {0, 0, 0, 0, 0, 0, 0, 0};

    for (int t = 0; t < 9; ++t) {
        int toff = ((t / 3 - 1) * W + (t % 3 - 1)) * ldin;
        bool v0 = (vmask[0] >> t) & 1u;
        bool v1 = (vmask[1] >> t) & 1u;
        const ushort_t* wp0 = wT + ((size_t)(t * CO + n0 + wc * 32 + fr)) * CI + fo;
        const ushort_t* wp1 = wp0 + (size_t)16 * CI;
#pragma unroll
        for (int kc = 0; kc < CI / 32; ++kc) {
            int k0 = kc * 32;
            bf16x8 a0 = v0 ? *(const bf16x8*)(in + abase[0] + toff + k0) : zz;
            bf16x8 a1 = v1 ? *(const bf16x8*)(in + abase[1] + toff + k0) : zz;
            bf16x8 b0 = *(const bf16x8*)(wp0 + k0);
            bf16x8 b1 = *(const bf16x8*)(wp1 + k0);
            acc[0][0] = __builtin_amdgcn_mfma_f32_16x16x32_bf16(a0, b0, acc[0][0], 0, 0, 0);
            acc[0][1] = __builtin_amdgcn_mfma_f32_16x16x32_bf16(a0, b1, acc[0][1], 0, 0, 0);
            acc[1][0] = __builtin_amdgcn_mfma_f32_16x16x32_bf16(a1, b0, acc[1][0], 0, 0, 0);
            acc[1][1] = __builtin_amdgcn_mfma_f32_16x16x32_bf16(a1, b1, acc[1][1], 0, 0, 0);
        }
    }

#pragma unroll
    for (int mi = 0; mi < 2; ++mi) {
#pragma unroll
        for (int ni = 0; ni < 2; ++ni) {
            int row0 = m0 + wr * 32 + mi * 16 + ((lane >> 4) << 2);
            int col = n0 + wc * 32 + ni * 16 + (lane & 15);
            float bv = bias[col];
#pragma unroll
            for (int r = 0; r < 4; ++r)
                out[(size_t)(row0 + r) * ldout + outoff + col] = f2bf(fmaxf(acc[mi][ni][r] + bv, 0.f));
        }
    }
}

// ---------- 2x2 maxpool NHWC bf16 ----------
__global__ void maxpool_nhwc_k(const ushort_t* __restrict__ in, ushort_t* __restrict__ out,
                               int C, int Hi, int Wi)
{
    int idx = blockIdx.x * 256 + threadIdx.x;
    int CG = C >> 3;
    int Wo = Wi >> 1, Ho = Hi >> 1;
    if (idx >= Ho * Wo * CG) return;
    int cg = idx % CG;
    int p = idx / CG;
    int y = p / Wo, x = p % Wo;
    const ushort_t* ip = in + ((size_t)(2 * y) * Wi + 2 * x) * C + cg * 8;
    bf16x8 v0 = *(const bf16x8*)(ip);
    bf16x8 v1 = *(const bf16x8*)(ip + C);
    bf16x8 v2 = *(const bf16x8*)(ip + (size_t)Wi * C);
    bf16x8 v3 = *(const bf16x8*)(ip + (size_t)Wi * C + C);
    bf16x8 r;
#pragma unroll
    for (int j = 0; j < 8; ++j) {
        float m = fmaxf(fmaxf(bf2f((ushort_t)v0[j]), bf2f((ushort_t)v1[j])),
                        fmaxf(bf2f((ushort_t)v2[j]), bf2f((ushort_t)v3[j])));
        r[j] = (short)f2bf(m);
    }
    *(bf16x8*)(out + (size_t)p * C + cg * 8) = r;
}

// ---------- bicubic weights (align_corners=True), PyTorch A=-0.75 ----------
__device__ inline void cubw(float t, float* w) {
    float x0 = 1.f + t, x2 = 1.f - t, x3 = 2.f - t;
    w[0] = ((-0.75f*x0 + 3.75f)*x0 - 6.f)*x0 + 3.f;
    w[1] = (1.25f*t - 2.25f)*t*t + 1.f;
    w[2] = (1.25f*x2 - 2.25f)*x2*x2 + 1.f;
    w[3] = ((-0.75f*x3 + 3.75f)*x3 - 6.f)*x3 + 3.f;
}

// ---------- bicubic 32->128 NHWC bf16 (256 ch) into F cols 64..319 ----------
__global__ __launch_bounds__(256) void bicubic_nhwc_k(const ushort_t* __restrict__ in, ushort_t* __restrict__ F)
{
    int idx = blockIdx.x * 256 + threadIdx.x;  // 16384 * 32
    int cg = idx & 31;
    int p = idx >> 5;
    int Y = p >> 7, X = p & 127;
    float sy = (float)Y * (31.f / 127.f);
    float sx = (float)X * (31.f / 127.f);
    int fy = (int)floorf(sy), fx = (int)floorf(sx);
    float ty = sy - (float)fy, tx = sx - (float)fx;
    float wy[4], wx[4];
    cubw(ty, wy); cubw(tx, wx);
    float a[8] = {0.f, 0.f, 0.f, 0.f, 0.f, 0.f, 0.f, 0.f};
#pragma unroll
    for (int i = 0; i < 4; ++i) {
        int yy = min(max(fy - 1 + i, 0), 31);
#pragma unroll
        for (int j = 0; j < 4; ++j) {
            int xx = min(max(fx - 1 + j, 0), 31);
            float w = wy[i] * wx[j];
            bf16x8 v = *(const bf16x8*)(in + ((size_t)yy * 32 + xx) * 256 + cg * 8);
#pragma unroll
            for (int e = 0; e < 8; ++e) a[e] += w * bf2f((ushort_t)v[e]);
        }
    }
    bf16x8 r;
#pragma unroll
    for (int e = 0; e < 8; ++e) r[e] = (short)f2bf(a[e]);
    *(bf16x8*)(F + (size_t)p * 320 + 64 + cg * 8) = r;
}

// ---------- in-place L2-normalize rows of F [16384][320] bf16 (wave per pixel) ----------
__global__ __launch_bounds__(256) void norm_k(ushort_t* __restrict__ F)
{
    int lane = threadIdx.x & 63;
    int p = blockIdx.x * 4 + (threadIdx.x >> 6);
    ushort_t* rp = F + (size_t)p * 320;
    bool act = lane < 40;
    bf16x8 v = {0, 0, 0, 0, 0, 0, 0, 0};
    float ss = 0.f;
    if (act) {
        v = *(const bf16x8*)(rp + lane * 8);
#pragma unroll
        for (int e = 0; e < 8; ++e) { float f = bf2f((ushort_t)v[e]); ss += f * f; }
    }
#pragma unroll
    for (int off = 32; off > 0; off >>= 1) ss += __shfl_xor(ss, off);
    float inv = 1.f / (1e-8f + sqrtf(ss));
    if (act) {
#pragma unroll
        for (int e = 0; e < 8; ++e) v[e] = (short)f2bf(bf2f((ushort_t)v[e]) * inv);
        *(bf16x8*)(rp + lane * 8) = v;
    }
}

// ---------- 2x2 mean pool on normalized F_ref -> Abuf [4096][320] bf16 ----------
__global__ void pool_ref_nhwc_k(const ushort_t* __restrict__ F, ushort_t* __restrict__ A)
{
    int idx = blockIdx.x * 256 + threadIdx.x;  // 4096*40
    if (idx >= 4096 * 40) return;
    int cg = idx % 40;
    int m = idx / 40;
    int y = m >> 6, x = m & 63;
    const ushort_t* ip = F + ((size_t)(2 * y) * 128 + 2 * x) * 320 + cg * 8;
    bf16x8 v0 = *(const bf16x8*)(ip);
    bf16x8 v1 = *(const bf16x8*)(ip + 320);
    bf16x8 v2 = *(const bf16x8*)(ip + 128 * 320);
    bf16x8 v3 = *(const bf16x8*)(ip + 128 * 320 + 320);
    bf16x8 r;
#pragma unroll
    for (int j = 0; j < 8; ++j) {
        float s = bf2f((ushort_t)v0[j]) + bf2f((ushort_t)v1[j]) + bf2f((ushort_t)v2[j]) + bf2f((ushort_t)v3[j]);
        r[j] = (short)f2bf(0.25f * s);
    }
    *(bf16x8*)(A + (size_t)m * 320 + cg * 8) = r;
}

// ---------- correlation GEMM: A[4096][320] x B[16384][320]^T -> dist bf16 [4096][16384] ----------
__global__ __launch_bounds__(256) void gemm_corr_k(
    const ushort_t* __restrict__ A, const ushort_t* __restrict__ B, ushort_t* __restrict__ D)
{
    __shared__ ushort_t lA[128 * 32];
    __shared__ ushort_t lB[128 * 32];
    const int tid = threadIdx.x;
    const int lane = tid & 63;
    const int wid = tid >> 6;
    const int wr = wid >> 1, wc = wid & 1;
    const int m0 = blockIdx.y * 128, n0 = blockIdx.x * 128;
    const int rS = tid >> 2;
    const int cS = (tid & 3) << 3;
    const int fr = lane & 15;
    const int fo = (lane >> 4) << 3;

    f32x4 zero = {0.f, 0.f, 0.f, 0.f};
    f32x4 acc[4][4];
#pragma unroll
    for (int i = 0; i < 4; ++i)
#pragma unroll
        for (int j = 0; j < 4; ++j) acc[i][j] = zero;

    for (int k0 = 0; k0 < 320; k0 += 32) {
        uint4 a0 = *(const uint4*)(A + (size_t)(m0 + rS) * 320 + k0 + cS);
        uint4 a1 = *(const uint4*)(A + (size_t)(m0 + 64 + rS) * 320 + k0 + cS);
        uint4 b0 = *(const uint4*)(B + (size_t)(n0 + rS) * 320 + k0 + cS);
        uint4 b1 = *(const uint4*)(B + (size_t)(n0 + 64 + rS) * 320 + k0 + cS);
        __syncthreads();
        *(uint4*)&lA[rS * 32 + cS] = a0;
        *(uint4*)&lA[(64 + rS) * 32 + cS] = a1;
        *(uint4*)&lB[rS * 32 + cS] = b0;
        *(uint4*)&lB[(64 + rS) * 32 + cS] = b1;
        __syncthreads();
        bf16x8 af[4], bfr[4];
#pragma unroll
        for (int mi = 0; mi < 4; ++mi)
            af[mi] = *(const bf16x8*)&lA[(wr * 64 + mi * 16 + fr) * 32 + fo];
#pragma unroll
        for (int ni = 0; ni < 4; ++ni)
            bfr[ni] = *(const bf16x8*)&lB[(wc * 64 + ni * 16 + fr) * 32 + fo];
#pragma unroll
        for (int mi = 0; mi < 4; ++mi)
#pragma unroll
            for (int ni = 0; ni < 4; ++ni)
                acc[mi][ni] = __builtin_amdgcn_mfma_f32_16x16x32_bf16(af[mi], bfr[ni], acc[mi][ni], 0, 0, 0);
    }
    const float s = 1.0f / 320.0f;
#pragma unroll
    for (int mi = 0; mi < 4; ++mi) {
#pragma unroll
        for (int ni = 0; ni < 4; ++ni) {
            int grow0 = m0 + wr * 64 + mi * 16 + ((lane >> 4) << 2);
            int gcol = n0 + wc * 64 + ni * 16 + (lane & 15);
#pragma unroll
            for (int r = 0; r < 4; ++r)
                D[(size_t)(grow0 + r) * 16384 + gcol] = f2bf(acc[mi][ni][r] * s);
        }
    }
}

// ---------- column sums of exp(cr*d) ----------
__global__ void col_partial_k(const ushort_t* __restrict__ Dist, const float* __restrict__ coefr,
                              float* __restrict__ psum)
{
    int chunk = blockIdx.y;
    int jj = blockIdx.x * 256 + threadIdx.x;
    float cr = coefr[0];
    int j = jj * 2;
    const ushort_t* cp = Dist + j;
    float s0 = 0.f, s1 = 0.f;
    int r0 = chunk * 512;
    for (int m = 0; m < 512; ++m) {
        uint_t u = *(const uint_t*)(cp + (size_t)(r0 + m) * 16384);
        s0 += expf(cr * bflo(u));
        s1 += expf(cr * bfhi(u));
    }
    psum[(size_t)chunk * 16384 + j] = s0;
    psum[(size_t)chunk * 16384 + j + 1] = s1;
}
__global__ void col_final_k(const float* __restrict__ psum, float* __restrict__ csum)
{
    int j = blockIdx.x * 256 + threadIdx.x;
    float s = 0.f;
#pragma unroll
    for (int k = 0; k < 8; ++k) s += psum[(size_t)k * 16384 + j];
    csum[j] = s;
}

// ---------- per-row: sum of exp(ct*d), conf + top-5 (one wave per row) ----------
#define INS5(w_) { float w = (w_); float mx; \
    mx = fmaxf(w, t0); w = fminf(w, t0); t0 = mx; \
    mx = fmaxf(w, t1); w = fminf(w, t1); t1 = mx; \
    mx = fmaxf(w, t2); w = fminf(w, t2); t2 = mx; \
    mx = fmaxf(w, t3); w = fminf(w, t3); t3 = mx; \
    t4 = fmaxf(w, t4); }

__global__ __launch_bounds__(256) void row_topk_k(
    const ushort_t* __restrict__ Dist, const float* __restrict__ csum,
    const float* __restrict__ coefr, const float* __restrict__ coeft,
    float* __restrict__ conf5)
{
    int wid = threadIdx.x >> 6, lane = threadIdx.x & 63;
    int row = blockIdx.x * 4 + wid;
    float cr = coefr[0], ct = coeft[0];
    const ushort_t* rp = Dist + (size_t)row * 16384;

    float s = 0.f;
    for (int i = 0; i < 32; ++i) {
        int col = (i * 64 + lane) * 8;
        uint4 u = *(const uint4*)(rp + col);
        s += expf(ct * bflo(u.x)) + expf(ct * bfhi(u.x));
        s += expf(ct * bflo(u.y)) + expf(ct * bfhi(u.y));
        s += expf(ct * bflo(u.z)) + expf(ct * bfhi(u.z));
        s += expf(ct * bflo(u.w)) + expf(ct * bfhi(u.w));
    }
#pragma unroll
    for (int off = 32; off > 0; off >>= 1) s += __shfl_xor(s, off);
    float rs = s;

    float hc = 0.5f * (cr + ct);
    float t0 = -1e30f, t1 = -1e30f, t2 = -1e30f, t3 = -1e30f, t4 = -1e30f;
    for (int i = 0; i < 32; ++i) {
        int col = (i * 64 + lane) * 8;
        uint4 u = *(const uint4*)(rp + col);
        float d0 = bflo(u.x), d1 = bfhi(u.x), d2 = bflo(u.y), d3 = bfhi(u.y);
        float d4 = bflo(u.z), d5 = bfhi(u.z), d6 = bflo(u.w), d7 = bfhi(u.w);
        INS5(expf(hc * d0) / sqrtf(csum[col+0] * rs));
        INS5(expf(hc * d1) / sqrtf(csum[col+1] * rs));
        INS5(expf(hc * d2) / sqrtf(csum[col+2] * rs));
        INS5(expf(hc * d3) / sqrtf(csum[col+3] * rs));
        INS5(expf(hc * d4) / sqrtf(csum[col+4] * rs));
        INS5(expf(hc * d5) / sqrtf(csum[col+5] * rs));
        INS5(expf(hc * d6) / sqrtf(csum[col+6] * rs));
        INS5(expf(hc * d7) / sqrtf(csum[col+7] * rs));
    }
#pragma unroll
    for (int off = 1; off < 64; off <<= 1) {
        float o0 = __shfl_xor(t0, off), o1 = __shfl_xor(t1, off), o2 = __shfl_xor(t2, off);
        float o3 = __shfl_xor(t3, off), o4 = __shfl_xor(t4, off);
        INS5(o0); INS5(o1); INS5(o2); INS5(o3); INS5(o4);
    }
    if (lane == 0) {
        conf5[0 * 4096 + row] = t0;
        conf5[1 * 4096 + row] = t1;
        conf5[2 * 4096 + row] = t2;
        conf5[3 * 4096 + row] = t3;
        conf5[4 * 4096 + row] = t4;
    }
}

// ---------- fp32 3x3 conv (head only, NCHW) ----------
__global__ void conv3x3_k(const float* __restrict__ in, const float* __restrict__ wgt,
                          const float* __restrict__ bias, float* __restrict__ out,
                          int Cin, int H, int W, int relu)
{
    int p = blockIdx.x * 256 + threadIdx.x;
    int HW = H * W;
    if (p >= HW) return;
    int co0 = blockIdx.y * 8;
    int y = p / W, x = p - y * W;
    float acc0 = bias[co0+0], acc1 = bias[co0+1], acc2 = bias[co0+2], acc3 = bias[co0+3];
    float acc4 = bias[co0+4], acc5 = bias[co0+5], acc6 = bias[co0+6], acc7 = bias[co0+7];
    bool ym = y > 0, yp = y < H-1, xm = x > 0, xp = x < W-1;
    for (int ci = 0; ci < Cin; ++ci) {
        const float* ip = in + (size_t)ci * HW + p;
        float v0 = (ym && xm) ? ip[-W-1] : 0.f;
        float v1 = (ym)       ? ip[-W]   : 0.f;
        float v2 = (ym && xp) ? ip[-W+1] : 0.f;
        float v3 = (xm)       ? ip[-1]   : 0.f;
        float v4 =              ip[0];
        float v5 = (xp)       ? ip[1]    : 0.f;
        float v6 = (yp && xm) ? ip[W-1]  : 0.f;
        float v7 = (yp)       ? ip[W]    : 0.f;
        float v8 = (yp && xp) ? ip[W+1]  : 0.f;
        const float* wp = wgt + ((size_t)co0 * Cin + ci) * 9;
        size_t ws = (size_t)Cin * 9;
#define CACC(q, a) { const float* wq = wp + q * ws; \
        a += wq[0]*v0 + wq[1]*v1 + wq[2]*v2 + wq[3]*v3 + wq[4]*v4 \
           + wq[5]*v5 + wq[6]*v6 + wq[7]*v7 + wq[8]*v8; }
        CACC(0, acc0) CACC(1, acc1) CACC(2, acc2) CACC(3, acc3)
        CACC(4, acc4) CACC(5, acc5) CACC(6, acc6) CACC(7, acc7)
#undef CACC
    }
#define CW(q, a) { float r = a; if (relu) r = fmaxf(r, 0.f); out[(size_t)(co0+q)*HW + p] = r; }
    CW(0, acc0) CW(1, acc1) CW(2, acc2) CW(3, acc3)
    CW(4, acc4) CW(5, acc5) CW(6, acc6) CW(7, acc7)
#undef CW
}

// ---------- fp32 bicubic (final output) ----------
__global__ void bicubic_k(const float* __restrict__ in, float* __restrict__ out,
                          int C, int Hin, int Win, int Hout, int Wout)
{
    int idx = blockIdx.x * 256 + threadIdx.x;
    int total = C * Hout * Wout;
    if (idx >= total) return;
    int X = idx % Wout;
    int Y = (idx / Wout) % Hout;
    int c = idx / (Wout * Hout);
    float sy = (float)Y * (float)(Hin - 1) / (float)(Hout - 1);
    float sx = (float)X * (float)(Win - 1) / (float)(Wout - 1);
    int fy = (int)floorf(sy), fx = (int)floorf(sx);
    float ty = sy - (float)fy, tx = sx - (float)fx;
    float wy[4], wx[4];
    cubw(ty, wy); cubw(tx, wx);
    const float* ip = in + (size_t)c * Hin * Win;
    float acc = 0.f;
#pragma unroll
    for (int i = 0; i < 4; ++i) {
        int yy = min(max(fy - 1 + i, 0), Hin - 1);
        float ra = 0.f;
#pragma unroll
        for (int j = 0; j < 4; ++j) {
            int xx = min(max(fx - 1 + j, 0), Win - 1);
            ra += wx[j] * ip[yy * Win + xx];
        }
        acc += wy[i] * ra;
    }
    out[idx] = acc;
}

// ---------- 1x1 conv, Cin->1 ----------
__global__ void conv1x1_k(const float* __restrict__ in, const float* __restrict__ w,
                          const float* __restrict__ b, float* __restrict__ out, int Cin, int HW)
{
    int p = blockIdx.x * 256 + threadIdx.x;
    if (p >= HW) return;
    float a = b[0];
    for (int c = 0; c < Cin; ++c) a += w[c] * in[(size_t)c * HW + p];
    out[p] = a;
}

// ---------- host ----------
extern "C" void kernel_launch(void* const* d_in, const int* in_sizes, int n_in,
                              void* d_out, int out_size, void* d_ws, size_t ws_size,
                              hipStream_t stream)
{
    const float* x_ref = (const float*)d_in[0];
    const float* x_tem = (const float*)d_in[1];
    const float* w0  = (const float*)d_in[2];   const float* b0  = (const float*)d_in[3];
    const float* w2  = (const float*)d_in[4];   const float* b2  = (const float*)d_in[5];
    const float* w5  = (const float*)d_in[6];   const float* b5  = (const float*)d_in[7];
    const float* w7  = (const float*)d_in[8];   const float* b7  = (const float*)d_in[9];
    const float* w10 = (const float*)d_in[10];  const float* b10 = (const float*)d_in[11];
    const float* w12 = (const float*)d_in[12];  const float* b12 = (const float*)d_in[13];
    const float* w14 = (const float*)d_in[14];  const float* b14 = (const float*)d_in[15];
    const float* coefr = (const float*)d_in[16];
    const float* coeft = (const float*)d_in[17];
    const float* fw1 = (const float*)d_in[18];  const float* fb1 = (const float*)d_in[19];
    const float* fw2 = (const float*)d_in[20];  const float* fb2 = (const float*)d_in[21];
    const float* fw3 = (const float*)d_in[22];  const float* fb3 = (const float*)d_in[23];
    float* out = (float*)d_out;

    char* wsp = (char*)d_ws;
    auto alloc = [&](size_t bytes) { char* p = wsp; wsp += (bytes + 255) & ~(size_t)255; return p; };
    ushort_t* F_ref = (ushort_t*)alloc((size_t)16384 * 320 * 2);
    ushort_t* F_tem = (ushort_t*)alloc((size_t)16384 * 320 * 2);
    ushort_t* t1    = (ushort_t*)alloc((size_t)16384 * 64 * 2);
    ushort_t* t2    = (ushort_t*)alloc((size_t)16384 * 64 * 2);
    ushort_t* wT2   = (ushort_t*)alloc((size_t)64 * 64 * 9 * 2);
    ushort_t* wT5   = (ushort_t*)alloc((size_t)128 * 64 * 9 * 2);
    ushort_t* wT7   = (ushort_t*)alloc((size_t)128 * 128 * 9 * 2);
    ushort_t* wT10  = (ushort_t*)alloc((size_t)256 * 128 * 9 * 2);
    ushort_t* wT12  = (ushort_t*)alloc((size_t)256 * 256 * 9 * 2);
    ushort_t* wT14  = (ushort_t*)alloc((size_t)256 * 256 * 9 * 2);
    ushort_t* Abuf  = (ushort_t*)alloc((size_t)4096 * 320 * 2);
    ushort_t* dist  = (ushort_t*)alloc((size_t)4096 * 16384 * 2);
    float*    psum  = (float*)alloc(8 * 16384 * 4);
    float*    csum  = (float*)alloc(16384 * 4);
    float*    conf5 = (float*)alloc(5 * 4096 * 4);
    float*    h1    = (float*)alloc(8 * 4096 * 4);
    float*    h2    = (float*)alloc(8 * 4096 * 4);
    float*    out64 = (float*)alloc(4096 * 4);
    (void)ws_size; (void)n_in; (void)in_sizes; (void)out_size;

    // weight transforms (tiny)
    wtrans_k<<<(64*64*9 + 255)/256, 256, 0, stream>>>(w2, wT2, 64, 64);
    wtrans_k<<<(128*64*9 + 255)/256, 256, 0, stream>>>(w5, wT5, 128, 64);
    wtrans_k<<<(128*128*9 + 255)/256, 256, 0, stream>>>(w7, wT7, 128, 128);
    wtrans_k<<<(256*128*9 + 255)/256, 256, 0, stream>>>(w10, wT10, 256, 128);
    wtrans_k<<<(256*256*9 + 255)/256, 256, 0, stream>>>(w12, wT12, 256, 256);
    wtrans_k<<<(256*256*9 + 255)/256, 256, 0, stream>>>(w14, wT14, 256, 256);

    auto features = [&](const float* x, ushort_t* F) {
        // conv0: 3->64 @128^2, writes F cols 0..63
        conv0_k<<<4096, 256, 0, stream>>>(x, w0, b0, F);
        // conv2: 64->64 @128^2 (reads F cols 0..63, ld 320)
        conv_mfma_k<64><<<dim3(256, 1), 256, 0, stream>>>(F, 320, 0, wT2, b2, t1, 64, 0, 128, 128, 64);
        // pool -> [64][64][64]
        maxpool_nhwc_k<<<128, 256, 0, stream>>>(t1, t2, 64, 128, 128);
        // conv5: 64->128 @64^2
        conv_mfma_k<64><<<dim3(64, 2), 256, 0, stream>>>(t2, 64, 0, wT5, b5, t1, 128, 0, 64, 64, 128);
        // conv7: 128->128 @64^2
        conv_mfma_k<128><<<dim3(64, 2), 256, 0, stream>>>(t1, 128, 0, wT7, b7, t2, 128, 0, 64, 64, 128);
        // pool -> [32][32][128]
        maxpool_nhwc_k<<<64, 256, 0, stream>>>(t2, t1, 128, 64, 64);
        // conv10: 128->256 @32^2
        conv_mfma_k<128><<<dim3(16, 4), 256, 0, stream>>>(t1, 128, 0, wT10, b10, t2, 256, 0, 32, 32, 256);
        // conv12: 256->256 @32^2
        conv_mfma_k<256><<<dim3(16, 4), 256, 0, stream>>>(t2, 256, 0, wT12, b12, t1, 256, 0, 32, 32, 256);
        // conv14: 256->256 @32^2
        conv_mfma_k<256><<<dim3(16, 4), 256, 0, stream>>>(t1, 256, 0, wT14, b14, t2, 256, 0, 32, 32, 256);
        // bicubic 32->128 into F cols 64..319
        bicubic_nhwc_k<<<2048, 256, 0, stream>>>(t2, F);
        // in-place L2 norm per pixel
        norm_k<<<4096, 256, 0, stream>>>(F);
    };

    features(x_ref, F_ref);
    features(x_tem, F_tem);
    pool_ref_nhwc_k<<<640, 256, 0, stream>>>(F_ref, Abuf);

    gemm_corr_k<<<dim3(128, 32), 256, 0, stream>>>(Abuf, F_tem, dist);

    col_partial_k<<<dim3(32, 8), 256, 0, stream>>>(dist, coefr, psum);
    col_final_k<<<64, 256, 0, stream>>>(psum, csum);
    row_topk_k<<<1024, 256, 0, stream>>>(dist, csum, coefr, coeft, conf5);

    conv3x3_k<<<dim3(16, 1), 256, 0, stream>>>(conf5, fw1, fb1, h1, 5, 64, 64, 1);
    conv3x3_k<<<dim3(16, 1), 256, 0, stream>>>(h1, fw2, fb2, h2, 8, 64, 64, 1);
    conv1x1_k<<<16, 256, 0, stream>>>(h2, fw3, fb3, out64, 8, 4096);
    bicubic_k<<<64, 256, 0, stream>>>(out64, out, 1, 64, 64, 128, 128);
}

// Round 3
// 417.093 us; speedup vs baseline: 5.3245x; 1.5328x over previous
//
#include <hip/hip_runtime.h>
#include <math.h>

typedef unsigned short ushort_t;
typedef unsigned int uint_t;
typedef __attribute__((ext_vector_type(8))) short bf16x8;
typedef __attribute__((ext_vector_type(4))) float f32x4;

#define FSTRIDE ((size_t)16384 * 320)
#define TSTRIDE ((size_t)16384 * 64)

// ---------- bf16 helpers ----------
__device__ inline ushort_t f2bf(float f) {
    union { float f; uint_t u; } x; x.f = f;
    uint_t r = x.u + 0x7fffu + ((x.u >> 16) & 1u);
    return (ushort_t)(r >> 16);
}
__device__ inline float bf2f(ushort_t h) {
    union { uint_t u; float f; } x; x.u = ((uint_t)h) << 16;
    return x.f;
}
__device__ inline float bflo(uint_t u) {
    union { uint_t u; float f; } x; x.u = u << 16; return x.f;
}
__device__ inline float bfhi(uint_t u) {
    union { uint_t u; float f; } x; x.u = u & 0xffff0000u; return x.f;
}

// ---------- weight transform: OIHW fp32 -> [tap][co][ci] bf16 ----------
__global__ void wtrans_k(const float* __restrict__ w, ushort_t* __restrict__ wT, int CO, int CI)
{
    int idx = blockIdx.x * 256 + threadIdx.x;
    if (idx >= CO * CI * 9) return;
    int tap = idx % 9;
    int rem = idx / 9;
    int ci = rem % CI;
    int co = rem / CI;
    wT[((size_t)tap * CO + co) * CI + ci] = f2bf(w[idx]);
}

// ---------- conv0: 3->64 @128x128, NCHW fp32 in, NHWC bf16 out (batched) ----------
__global__ __launch_bounds__(256) void conv0_k(const float* __restrict__ x0, const float* __restrict__ x1,
                                               const float* __restrict__ w,
                                               const float* __restrict__ b, ushort_t* __restrict__ F)
{
    const float* x = blockIdx.y ? x1 : x0;
    F += (size_t)blockIdx.y * FSTRIDE;
    int co = threadIdx.x & 63;
    int p = blockIdx.x * 4 + (threadIdx.x >> 6);
    int y = p >> 7, xx = p & 127;
    float acc = b[co];
#pragma unroll
    for (int ci = 0; ci < 3; ++ci) {
#pragma unroll
        for (int t = 0; t < 9; ++t) {
            int dy = t / 3 - 1, dx = t % 3 - 1;
            int yy = y + dy, xc = xx + dx;
            if ((unsigned)yy < 128u && (unsigned)xc < 128u) {
                acc += x[ci * 16384 + yy * 128 + xc] * w[co * 27 + ci * 9 + t];
            }
        }
    }
    F[(size_t)p * 320 + co] = f2bf(fmaxf(acc, 0.f));
}

// ---------- implicit-GEMM MFMA conv 3x3 pad=1: NHWC bf16, relu (batched via blockIdx.z) ----------
template<int CI>
__global__ __launch_bounds__(256) void conv_mfma_k(
    const ushort_t* __restrict__ in, int ldin, int inoff, size_t inImgStride,
    const ushort_t* __restrict__ wT, const float* __restrict__ bias,
    ushort_t* __restrict__ out, int ldout, int outoff, size_t outImgStride,
    int H, int W, int CO)
{
    in += (size_t)blockIdx.z * inImgStride;
    out += (size_t)blockIdx.z * outImgStride;
    const int tid = threadIdx.x;
    const int lane = tid & 63, wid = tid >> 6;
    const int wr = wid >> 1, wc = wid & 1;
    const int m0 = blockIdx.x * 64;
    const int n0 = blockIdx.y * 64;
    const int fr = lane & 15;
    const int fo = (lane >> 4) << 3;

    size_t abase[2];
    unsigned vmask[2];
#pragma unroll
    for (int mi = 0; mi < 2; ++mi) {
        int p = m0 + wr * 32 + mi * 16 + fr;
        int y = p / W, x = p % W;
        abase[mi] = (size_t)p * ldin + inoff + fo;
        unsigned vm = 0;
#pragma unroll
        for (int t = 0; t < 9; ++t) {
            int dy = t / 3 - 1, dx = t % 3 - 1;
            if ((unsigned)(y + dy) < (unsigned)H && (unsigned)(x + dx) < (unsigned)W) vm |= 1u << t;
        }
        vmask[mi] = vm;
    }

    f32x4 zero = {0.f, 0.f, 0.f, 0.f};
    f32x4 acc[2][2] = {{zero, zero}, {zero, zero}};
    const bf16x8 zz = {0, 0, 0, 0, 0, 0, 0, 0};

    for (int t = 0; t < 9; ++t) {
        int toff = ((t / 3 - 1) * W + (t % 3 - 1)) * ldin;
        bool v0 = (vmask[0] >> t) & 1u;
        bool v1 = (vmask[1] >> t) & 1u;
        const ushort_t* wp0 = wT + ((size_t)(t * CO + n0 + wc * 32 + fr)) * CI + fo;
        const ushort_t* wp1 = wp0 + (size_t)16 * CI;
#pragma unroll
        for (int kc = 0; kc < CI / 32; ++kc) {
            int k0 = kc * 32;
            bf16x8 a0 = v0 ? *(const bf16x8*)(in + abase[0] + toff + k0) : zz;
            bf16x8 a1 = v1 ? *(const bf16x8*)(in + abase[1] + toff + k0) : zz;
            bf16x8 b0 = *(const bf16x8*)(wp0 + k0);
            bf16x8 b1 = *(const bf16x8*)(wp1 + k0);
            acc[0][0] = __builtin_amdgcn_mfma_f32_16x16x32_bf16(a0, b0, acc[0][0], 0, 0, 0);
            acc[0][1] = __builtin_amdgcn_mfma_f32_16x16x32_bf16(a0, b1, acc[0][1], 0, 0, 0);
            acc[1][0] = __builtin_amdgcn_mfma_f32_16x16x32_bf16(a1, b0, acc[1][0], 0, 0, 0);
            acc[1][1] = __builtin_amdgcn_mfma_f32_16x16x32_bf16(a1, b1, acc[1][1], 0, 0, 0);
        }
    }

#pragma unroll
    for (int mi = 0; mi < 2; ++mi) {
#pragma unroll
        for (int ni = 0; ni < 2; ++ni) {
            int row0 = m0 + wr * 32 + mi * 16 + ((lane >> 4) << 2);
            int col = n0 + wc * 32 + ni * 16 + (lane & 15);
            float bv = bias[col];
#pragma unroll
            for (int r = 0; r < 4; ++r)
                out[(size_t)(row0 + r) * ldout + outoff + col] = f2bf(fmaxf(acc[mi][ni][r] + bv, 0.f));
        }
    }
}

// ---------- 2x2 maxpool NHWC bf16 (batched via blockIdx.y) ----------
__global__ void maxpool_nhwc_k(const ushort_t* __restrict__ in, ushort_t* __restrict__ out,
                               int C, int Hi, int Wi)
{
    in += (size_t)blockIdx.y * TSTRIDE;
    out += (size_t)blockIdx.y * TSTRIDE;
    int idx = blockIdx.x * 256 + threadIdx.x;
    int CG = C >> 3;
    int Wo = Wi >> 1, Ho = Hi >> 1;
    if (idx >= Ho * Wo * CG) return;
    int cg = idx % CG;
    int p = idx / CG;
    int y = p / Wo, x = p % Wo;
    const ushort_t* ip = in + ((size_t)(2 * y) * Wi + 2 * x) * C + cg * 8;
    bf16x8 v0 = *(const bf16x8*)(ip);
    bf16x8 v1 = *(const bf16x8*)(ip + C);
    bf16x8 v2 = *(const bf16x8*)(ip + (size_t)Wi * C);
    bf16x8 v3 = *(const bf16x8*)(ip + (size_t)Wi * C + C);
    bf16x8 r;
#pragma unroll
    for (int j = 0; j < 8; ++j) {
        float m = fmaxf(fmaxf(bf2f((ushort_t)v0[j]), bf2f((ushort_t)v1[j])),
                        fmaxf(bf2f((ushort_t)v2[j]), bf2f((ushort_t)v3[j])));
        r[j] = (short)f2bf(m);
    }
    *(bf16x8*)(out + (size_t)p * C + cg * 8) = r;
}

// ---------- bicubic weights (align_corners=True), PyTorch A=-0.75 ----------
__device__ inline void cubw(float t, float* w) {
    float x0 = 1.f + t, x2 = 1.f - t, x3 = 2.f - t;
    w[0] = ((-0.75f*x0 + 3.75f)*x0 - 6.f)*x0 + 3.f;
    w[1] = (1.25f*t - 2.25f)*t*t + 1.f;
    w[2] = (1.25f*x2 - 2.25f)*x2*x2 + 1.f;
    w[3] = ((-0.75f*x3 + 3.75f)*x3 - 6.f)*x3 + 3.f;
}

// ---------- bicubic 32->128 NHWC bf16 (256 ch) into F cols 64..319 (batched) ----------
__global__ __launch_bounds__(256) void bicubic_nhwc_k(const ushort_t* __restrict__ in, ushort_t* __restrict__ F)
{
    in += (size_t)blockIdx.y * TSTRIDE;
    F += (size_t)blockIdx.y * FSTRIDE;
    int idx = blockIdx.x * 256 + threadIdx.x;
    int cg = idx & 31;
    int p = idx >> 5;
    int Y = p >> 7, X = p & 127;
    float sy = (float)Y * (31.f / 127.f);
    float sx = (float)X * (31.f / 127.f);
    int fy = (int)floorf(sy), fx = (int)floorf(sx);
    float ty = sy - (float)fy, tx = sx - (float)fx;
    float wy[4], wx[4];
    cubw(ty, wy); cubw(tx, wx);
    float a[8] = {0.f, 0.f, 0.f, 0.f, 0.f, 0.f, 0.f, 0.f};
#pragma unroll
    for (int i = 0; i < 4; ++i) {
        int yy = min(max(fy - 1 + i, 0), 31);
#pragma unroll
        for (int j = 0; j < 4; ++j) {
            int xx = min(max(fx - 1 + j, 0), 31);
            float w = wy[i] * wx[j];
            bf16x8 v = *(const bf16x8*)(in + ((size_t)yy * 32 + xx) * 256 + cg * 8);
#pragma unroll
            for (int e = 0; e < 8; ++e) a[e] += w * bf2f((ushort_t)v[e]);
        }
    }
    bf16x8 r;
#pragma unroll
    for (int e = 0; e < 8; ++e) r[e] = (short)f2bf(a[e]);
    *(bf16x8*)(F + (size_t)p * 320 + 64 + cg * 8) = r;
}

// ---------- in-place L2-normalize rows of F [2*16384][320] bf16 (wave per pixel) ----------
__global__ __launch_bounds__(256) void norm_k(ushort_t* __restrict__ F)
{
    int lane = threadIdx.x & 63;
    int p = blockIdx.x * 4 + (threadIdx.x >> 6);
    ushort_t* rp = F + (size_t)p * 320;
    bool act = lane < 40;
    bf16x8 v = {0, 0, 0, 0, 0, 0, 0, 0};
    float ss = 0.f;
    if (act) {
        v = *(const bf16x8*)(rp + lane * 8);
#pragma unroll
        for (int e = 0; e < 8; ++e) { float f = bf2f((ushort_t)v[e]); ss += f * f; }
    }
#pragma unroll
    for (int off = 32; off > 0; off >>= 1) ss += __shfl_xor(ss, off);
    float inv = 1.f / (1e-8f + sqrtf(ss));
    if (act) {
#pragma unroll
        for (int e = 0; e < 8; ++e) v[e] = (short)f2bf(bf2f((ushort_t)v[e]) * inv);
        *(bf16x8*)(rp + lane * 8) = v;
    }
}

// ---------- 2x2 mean pool on normalized F_ref -> Abuf [4096][320] bf16 ----------
__global__ void pool_ref_nhwc_k(const ushort_t* __restrict__ F, ushort_t* __restrict__ A)
{
    int idx = blockIdx.x * 256 + threadIdx.x;
    if (idx >= 4096 * 40) return;
    int cg = idx % 40;
    int m = idx / 40;
    int y = m >> 6, x = m & 63;
    const ushort_t* ip = F + ((size_t)(2 * y) * 128 + 2 * x) * 320 + cg * 8;
    bf16x8 v0 = *(const bf16x8*)(ip);
    bf16x8 v1 = *(const bf16x8*)(ip + 320);
    bf16x8 v2 = *(const bf16x8*)(ip + 128 * 320);
    bf16x8 v3 = *(const bf16x8*)(ip + 128 * 320 + 320);
    bf16x8 r;
#pragma unroll
    for (int j = 0; j < 8; ++j) {
        float s = bf2f((ushort_t)v0[j]) + bf2f((ushort_t)v1[j]) + bf2f((ushort_t)v2[j]) + bf2f((ushort_t)v3[j]);
        r[j] = (short)f2bf(0.25f * s);
    }
    *(bf16x8*)(A + (size_t)m * 320 + cg * 8) = r;
}

// ---------- correlation GEMM + fused softmax-denominator partials ----------
// A[4096][320] x B[16384][320]^T -> dist bf16 [4096][16384] (scaled 1/320)
// rpsum[nb=128][4096]: partial row sums of exp(ct*d); cpsum[mb=32][16384]: partial col sums of exp(cr*d)
__global__ __launch_bounds__(256) void gemm_corr_k(
    const ushort_t* __restrict__ A, const ushort_t* __restrict__ B, ushort_t* __restrict__ D,
    const float* __restrict__ coefr, const float* __restrict__ coeft,
    float* __restrict__ rpsum, float* __restrict__ cpsum)
{
    __shared__ ushort_t lA[128 * 32];
    __shared__ ushort_t lB[128 * 32];
    __shared__ float cl[2][128];
    __shared__ float rl[2][128];
    const int tid = threadIdx.x;
    const int lane = tid & 63;
    const int wid = tid >> 6;
    const int wr = wid >> 1, wc = wid & 1;
    const int m0 = blockIdx.y * 128, n0 = blockIdx.x * 128;
    const int rS = tid >> 2;
    const int cS = (tid & 3) << 3;
    const int fr = lane & 15;
    const int fo = (lane >> 4) << 3;

    f32x4 zero = {0.f, 0.f, 0.f, 0.f};
    f32x4 acc[4][4];
#pragma unroll
    for (int i = 0; i < 4; ++i)
#pragma unroll
        for (int j = 0; j < 4; ++j) acc[i][j] = zero;

    for (int k0 = 0; k0 < 320; k0 += 32) {
        uint4 a0 = *(const uint4*)(A + (size_t)(m0 + rS) * 320 + k0 + cS);
        uint4 a1 = *(const uint4*)(A + (size_t)(m0 + 64 + rS) * 320 + k0 + cS);
        uint4 b0 = *(const uint4*)(B + (size_t)(n0 + rS) * 320 + k0 + cS);
        uint4 b1 = *(const uint4*)(B + (size_t)(n0 + 64 + rS) * 320 + k0 + cS);
        __syncthreads();
        *(uint4*)&lA[rS * 32 + cS] = a0;
        *(uint4*)&lA[(64 + rS) * 32 + cS] = a1;
        *(uint4*)&lB[rS * 32 + cS] = b0;
        *(uint4*)&lB[(64 + rS) * 32 + cS] = b1;
        __syncthreads();
        bf16x8 af[4], bfr[4];
#pragma unroll
        for (int mi = 0; mi < 4; ++mi)
            af[mi] = *(const bf16x8*)&lA[(wr * 64 + mi * 16 + fr) * 32 + fo];
#pragma unroll
        for (int ni = 0; ni < 4; ++ni)
            bfr[ni] = *(const bf16x8*)&lB[(wc * 64 + ni * 16 + fr) * 32 + fo];
#pragma unroll
        for (int mi = 0; mi < 4; ++mi)
#pragma unroll
            for (int ni = 0; ni < 4; ++ni)
                acc[mi][ni] = __builtin_amdgcn_mfma_f32_16x16x32_bf16(af[mi], bfr[ni], acc[mi][ni], 0, 0, 0);
    }

    const float s = 1.0f / 320.0f;
    const float cr = coefr[0], ct = coeft[0];
    float cp[4] = {0.f, 0.f, 0.f, 0.f};
    float rp[4][4];
#pragma unroll
    for (int mi = 0; mi < 4; ++mi)
#pragma unroll
        for (int r = 0; r < 4; ++r) rp[mi][r] = 0.f;

#pragma unroll
    for (int mi = 0; mi < 4; ++mi) {
#pragma unroll
        for (int ni = 0; ni < 4; ++ni) {
            int grow0 = m0 + wr * 64 + mi * 16 + ((lane >> 4) << 2);
            int gcol = n0 + wc * 64 + ni * 16 + (lane & 15);
#pragma unroll
            for (int r = 0; r < 4; ++r) {
                float d = acc[mi][ni][r] * s;
                D[(size_t)(grow0 + r) * 16384 + gcol] = f2bf(d);
                cp[ni] += __expf(cr * d);
                rp[mi][r] += __expf(ct * d);
            }
        }
    }
    // reduce col partials across the 4 row-groups (lane>>4)
#pragma unroll
    for (int ni = 0; ni < 4; ++ni) {
        cp[ni] += __shfl_xor(cp[ni], 16);
        cp[ni] += __shfl_xor(cp[ni], 32);
    }
    if (lane < 16) {
#pragma unroll
        for (int ni = 0; ni < 4; ++ni)
            cl[wr][wc * 64 + ni * 16 + lane] = cp[ni];
    }
    // reduce row partials across the 16 col-lanes (lane&15)
#pragma unroll
    for (int mi = 0; mi < 4; ++mi)
#pragma unroll
        for (int r = 0; r < 4; ++r) {
            rp[mi][r] += __shfl_xor(rp[mi][r], 1);
            rp[mi][r] += __shfl_xor(rp[mi][r], 2);
            rp[mi][r] += __shfl_xor(rp[mi][r], 4);
            rp[mi][r] += __shfl_xor(rp[mi][r], 8);
        }
    if ((lane & 15) == 0) {
        int g = lane >> 4;
#pragma unroll
        for (int mi = 0; mi < 4; ++mi)
#pragma unroll
            for (int r = 0; r < 4; ++r)
                rl[wc][wr * 64 + mi * 16 + g * 4 + r] = rp[mi][r];
    }
    __syncthreads();
    if (tid < 128) {
        cpsum[(size_t)blockIdx.y * 16384 + n0 + tid] = cl[0][tid] + cl[1][tid];
        rpsum[(size_t)blockIdx.x * 4096 + m0 + tid] = rl[0][tid] + rl[1][tid];
    }
}

// ---------- finalize: lc[j] = -0.5*log(colsum), invr[m] = rsqrt(rowsum) ----------
__global__ void colfin_k(const float* __restrict__ cpsum, float* __restrict__ lc)
{
    int j = blockIdx.x * 256 + threadIdx.x;
    float s = 0.f;
#pragma unroll
    for (int k = 0; k < 32; ++k) s += cpsum[(size_t)k * 16384 + j];
    lc[j] = -0.5f * __logf(s);
}
__global__ void rowfin_k(const float* __restrict__ rpsum, float* __restrict__ invr)
{
    int m = blockIdx.x * 256 + threadIdx.x;
    float s = 0.f;
#pragma unroll
    for (int k = 0; k < 128; ++k) s += rpsum[(size_t)k * 4096 + m];
    invr[m] = rsqrtf(s);
}

// ---------- per-row top-5 in key space: key = hc*d + lc[j] (one wave per row) ----------
#define INS5(w_) { float w = (w_); float mx; \
    mx = fmaxf(w, t0); w = fminf(w, t0); t0 = mx; \
    mx = fmaxf(w, t1); w = fminf(w, t1); t1 = mx; \
    mx = fmaxf(w, t2); w = fminf(w, t2); t2 = mx; \
    mx = fmaxf(w, t3); w = fminf(w, t3); t3 = mx; \
    t4 = fmaxf(w, t4); }

__global__ __launch_bounds__(256) void row_topk_k(
    const ushort_t* __restrict__ Dist, const float* __restrict__ lc,
    const float* __restrict__ invr,
    const float* __restrict__ coefr, const float* __restrict__ coeft,
    float* __restrict__ conf5)
{
    int wid = threadIdx.x >> 6, lane = threadIdx.x & 63;
    int row = blockIdx.x * 4 + wid;
    float hc = 0.5f * (coefr[0] + coeft[0]);
    const ushort_t* rp = Dist + (size_t)row * 16384;

    float t0 = -1e30f, t1 = -1e30f, t2 = -1e30f, t3 = -1e30f, t4 = -1e30f;
    for (int i = 0; i < 32; ++i) {
        int col = (i * 64 + lane) * 8;
        uint4 u = *(const uint4*)(rp + col);
        float4 l0 = *(const float4*)(lc + col);
        float4 l1 = *(const float4*)(lc + col + 4);
        INS5(fmaf(hc, bflo(u.x), l0.x));
        INS5(fmaf(hc, bfhi(u.x), l0.y));
        INS5(fmaf(hc, bflo(u.y), l0.z));
        INS5(fmaf(hc, bfhi(u.y), l0.w));
        INS5(fmaf(hc, bflo(u.z), l1.x));
        INS5(fmaf(hc, bfhi(u.z), l1.y));
        INS5(fmaf(hc, bflo(u.w), l1.z));
        INS5(fmaf(hc, bfhi(u.w), l1.w));
    }
#pragma unroll
    for (int off = 1; off < 64; off <<= 1) {
        float o0 = __shfl_xor(t0, off), o1 = __shfl_xor(t1, off), o2 = __shfl_xor(t2, off);
        float o3 = __shfl_xor(t3, off), o4 = __shfl_xor(t4, off);
        INS5(o0); INS5(o1); INS5(o2); INS5(o3); INS5(o4);
    }
    if (lane == 0) {
        float iv = invr[row];
        conf5[0 * 4096 + row] = __expf(t0) * iv;
        conf5[1 * 4096 + row] = __expf(t1) * iv;
        conf5[2 * 4096 + row] = __expf(t2) * iv;
        conf5[3 * 4096 + row] = __expf(t3) * iv;
        conf5[4 * 4096 + row] = __expf(t4) * iv;
    }
}

// ---------- fp32 3x3 conv (head only, NCHW) ----------
__global__ void conv3x3_k(const float* __restrict__ in, const float* __restrict__ wgt,
                          const float* __restrict__ bias, float* __restrict__ out,
                          int Cin, int H, int W, int relu)
{
    int p = blockIdx.x * 256 + threadIdx.x;
    int HW = H * W;
    if (p >= HW) return;
    int co0 = blockIdx.y * 8;
    int y = p / W, x = p - y * W;
    float acc0 = bias[co0+0], acc1 = bias[co0+1], acc2 = bias[co0+2], acc3 = bias[co0+3];
    float acc4 = bias[co0+4], acc5 = bias[co0+5], acc6 = bias[co0+6], acc7 = bias[co0+7];
    bool ym = y > 0, yp = y < H-1, xm = x > 0, xp = x < W-1;
    for (int ci = 0; ci < Cin; ++ci) {
        const float* ip = in + (size_t)ci * HW + p;
        float v0 = (ym && xm) ? ip[-W-1] : 0.f;
        float v1 = (ym)       ? ip[-W]   : 0.f;
        float v2 = (ym && xp) ? ip[-W+1] : 0.f;
        float v3 = (xm)       ? ip[-1]   : 0.f;
        float v4 =              ip[0];
        float v5 = (xp)       ? ip[1]    : 0.f;
        float v6 = (yp && xm) ? ip[W-1]  : 0.f;
        float v7 = (yp)       ? ip[W]    : 0.f;
        float v8 = (yp && xp) ? ip[W+1]  : 0.f;
        const float* wp = wgt + ((size_t)co0 * Cin + ci) * 9;
        size_t ws = (size_t)Cin * 9;
#define CACC(q, a) { const float* wq = wp + q * ws; \
        a += wq[0]*v0 + wq[1]*v1 + wq[2]*v2 + wq[3]*v3 + wq[4]*v4 \
           + wq[5]*v5 + wq[6]*v6 + wq[7]*v7 + wq[8]*v8; }
        CACC(0, acc0) CACC(1, acc1) CACC(2, acc2) CACC(3, acc3)
        CACC(4, acc4) CACC(5, acc5) CACC(6, acc6) CACC(7, acc7)
#undef CACC
    }
#define CW(q, a) { float r = a; if (relu) r = fmaxf(r, 0.f); out[(size_t)(co0+q)*HW + p] = r; }
    CW(0, acc0) CW(1, acc1) CW(2, acc2) CW(3, acc3)
    CW(4, acc4) CW(5, acc5) CW(6, acc6) CW(7, acc7)
#undef CW
}

// ---------- fp32 bicubic (final output) ----------
__global__ void bicubic_k(const float* __restrict__ in, float* __restrict__ out,
                          int C, int Hin, int Win, int Hout, int Wout)
{
    int idx = blockIdx.x * 256 + threadIdx.x;
    int total = C * Hout * Wout;
    if (idx >= total) return;
    int X = idx % Wout;
    int Y = (idx / Wout) % Hout;
    int c = idx / (Wout * Hout);
    float sy = (float)Y * (float)(Hin - 1) / (float)(Hout - 1);
    float sx = (float)X * (float)(Win - 1) / (float)(Wout - 1);
    int fy = (int)floorf(sy), fx = (int)floorf(sx);
    float ty = sy - (float)fy, tx = sx - (float)fx;
    float wy[4], wx[4];
    cubw(ty, wy); cubw(tx, wx);
    const float* ip = in + (size_t)c * Hin * Win;
    float acc = 0.f;
#pragma unroll
    for (int i = 0; i < 4; ++i) {
        int yy = min(max(fy - 1 + i, 0), Hin - 1);
        float ra = 0.f;
#pragma unroll
        for (int j = 0; j < 4; ++j) {
            int xx = min(max(fx - 1 + j, 0), Win - 1);
            ra += wx[j] * ip[yy * Win + xx];
        }
        acc += wy[i] * ra;
    }
    out[idx] = acc;
}

// ---------- 1x1 conv, Cin->1 ----------
__global__ void conv1x1_k(const float* __restrict__ in, const float* __restrict__ w,
                          const float* __restrict__ b, float* __restrict__ out, int Cin, int HW)
{
    int p = blockIdx.x * 256 + threadIdx.x;
    if (p >= HW) return;
    float a = b[0];
    for (int c = 0; c < Cin; ++c) a += w[c] * in[(size_t)c * HW + p];
    out[p] = a;
}

// ---------- host ----------
extern "C" void kernel_launch(void* const* d_in, const int* in_sizes, int n_in,
                              void* d_out, int out_size, void* d_ws, size_t ws_size,
                              hipStream_t stream)
{
    const float* x_ref = (const float*)d_in[0];
    const float* x_tem = (const float*)d_in[1];
    const float* w0  = (const float*)d_in[2];   const float* b0  = (const float*)d_in[3];
    const float* w2  = (const float*)d_in[4];   const float* b2  = (const float*)d_in[5];
    const float* w5  = (const float*)d_in[6];   const float* b5  = (const float*)d_in[7];
    const float* w7  = (const float*)d_in[8];   const float* b7  = (const float*)d_in[9];
    const float* w10 = (const float*)d_in[10];  const float* b10 = (const float*)d_in[11];
    const float* w12 = (const float*)d_in[12];  const float* b12 = (const float*)d_in[13];
    const float* w14 = (const float*)d_in[14];  const float* b14 = (const float*)d_in[15];
    const float* coefr = (const float*)d_in[16];
    const float* coeft = (const float*)d_in[17];
    const float* fw1 = (const float*)d_in[18];  const float* fb1 = (const float*)d_in[19];
    const float* fw2 = (const float*)d_in[20];  const float* fb2 = (const float*)d_in[21];
    const float* fw3 = (const float*)d_in[22];  const float* fb3 = (const float*)d_in[23];
    float* out = (float*)d_out;

    char* wsp = (char*)d_ws;
    auto alloc = [&](size_t bytes) { char* p = wsp; wsp += (bytes + 255) & ~(size_t)255; return p; };
    ushort_t* F     = (ushort_t*)alloc(2 * FSTRIDE * 2);   // [2][16384][320]
    ushort_t* t1    = (ushort_t*)alloc(2 * TSTRIDE * 2);
    ushort_t* t2    = (ushort_t*)alloc(2 * TSTRIDE * 2);
    ushort_t* wT2   = (ushort_t*)alloc((size_t)64 * 64 * 9 * 2);
    ushort_t* wT5   = (ushort_t*)alloc((size_t)128 * 64 * 9 * 2);
    ushort_t* wT7   = (ushort_t*)alloc((size_t)128 * 128 * 9 * 2);
    ushort_t* wT10  = (ushort_t*)alloc((size_t)256 * 128 * 9 * 2);
    ushort_t* wT12  = (ushort_t*)alloc((size_t)256 * 256 * 9 * 2);
    ushort_t* wT14  = (ushort_t*)alloc((size_t)256 * 256 * 9 * 2);
    ushort_t* Abuf  = (ushort_t*)alloc((size_t)4096 * 320 * 2);
    ushort_t* dist  = (ushort_t*)alloc((size_t)4096 * 16384 * 2);
    float*    rpsum = (float*)alloc((size_t)128 * 4096 * 4);
    float*    cpsum = (float*)alloc((size_t)32 * 16384 * 4);
    float*    lc    = (float*)alloc(16384 * 4);
    float*    invr  = (float*)alloc(4096 * 4);
    float*    conf5 = (float*)alloc(5 * 4096 * 4);
    float*    h1    = (float*)alloc(8 * 4096 * 4);
    float*    h2    = (float*)alloc(8 * 4096 * 4);
    float*    out64 = (float*)alloc(4096 * 4);
    (void)ws_size; (void)n_in; (void)in_sizes; (void)out_size;

    // weight transforms (tiny)
    wtrans_k<<<(64*64*9 + 255)/256, 256, 0, stream>>>(w2, wT2, 64, 64);
    wtrans_k<<<(128*64*9 + 255)/256, 256, 0, stream>>>(w5, wT5, 128, 64);
    wtrans_k<<<(128*128*9 + 255)/256, 256, 0, stream>>>(w7, wT7, 128, 128);
    wtrans_k<<<(256*128*9 + 255)/256, 256, 0, stream>>>(w10, wT10, 256, 128);
    wtrans_k<<<(256*256*9 + 255)/256, 256, 0, stream>>>(w12, wT12, 256, 256);
    wtrans_k<<<(256*256*9 + 255)/256, 256, 0, stream>>>(w14, wT14, 256, 256);

    // batched feature extraction (img 0 = ref, img 1 = template)
    conv0_k<<<dim3(4096, 2), 256, 0, stream>>>(x_ref, x_tem, w0, b0, F);
    conv_mfma_k<64><<<dim3(256, 1, 2), 256, 0, stream>>>(F, 320, 0, FSTRIDE, wT2, b2, t1, 64, 0, TSTRIDE, 128, 128, 64);
    maxpool_nhwc_k<<<dim3(128, 2), 256, 0, stream>>>(t1, t2, 64, 128, 128);
    conv_mfma_k<64><<<dim3(64, 2, 2), 256, 0, stream>>>(t2, 64, 0, TSTRIDE, wT5, b5, t1, 128, 0, TSTRIDE, 64, 64, 128);
    conv_mfma_k<128><<<dim3(64, 2, 2), 256, 0, stream>>>(t1, 128, 0, TSTRIDE, wT7, b7, t2, 128, 0, TSTRIDE, 64, 64, 128);
    maxpool_nhwc_k<<<dim3(64, 2), 256, 0, stream>>>(t2, t1, 128, 64, 64);
    conv_mfma_k<128><<<dim3(16, 4, 2), 256, 0, stream>>>(t1, 128, 0, TSTRIDE, wT10, b10, t2, 256, 0, TSTRIDE, 32, 32, 256);
    conv_mfma_k<256><<<dim3(16, 4, 2), 256, 0, stream>>>(t2, 256, 0, TSTRIDE, wT12, b12, t1, 256, 0, TSTRIDE, 32, 32, 256);
    conv_mfma_k<256><<<dim3(16, 4, 2), 256, 0, stream>>>(t1, 256, 0, TSTRIDE, wT14, b14, t2, 256, 0, TSTRIDE, 32, 32, 256);
    bicubic_nhwc_k<<<dim3(2048, 2), 256, 0, stream>>>(t2, F);
    norm_k<<<8192, 256, 0, stream>>>(F);

    pool_ref_nhwc_k<<<640, 256, 0, stream>>>(F, Abuf);

    // correlation GEMM with fused softmax-denominator partials
    gemm_corr_k<<<dim3(128, 32), 256, 0, stream>>>(Abuf, F + FSTRIDE, dist, coefr, coeft, rpsum, cpsum);

    colfin_k<<<64, 256, 0, stream>>>(cpsum, lc);
    rowfin_k<<<16, 256, 0, stream>>>(rpsum, invr);

    // fused key-space top-5
    row_topk_k<<<1024, 256, 0, stream>>>(dist, lc, invr, coefr, coeft, conf5);

    conv3x3_k<<<dim3(16, 1), 256, 0, stream>>>(conf5, fw1, fb1, h1, 5, 64, 64, 1);
    conv3x3_k<<<dim3(16, 1), 256, 0, stream>>>(h1, fw2, fb2, h2, 8, 64, 64, 1);
    conv1x1_k<<<16, 256, 0, stream>>>(h2, fw3, fb3, out64, 8, 4096);
    bicubic_k<<<64, 256, 0, stream>>>(out64, out, 1, 64, 64, 128, 128);
}

// Round 4
// 409.737 us; speedup vs baseline: 5.4201x; 1.0180x over previous
//
#include <hip/hip_runtime.h>
#include <math.h>

typedef unsigned short ushort_t;
typedef unsigned int uint_t;
typedef __attribute__((ext_vector_type(8))) short bf16x8;
typedef __attribute__((ext_vector_type(4))) float f32x4;

#define FSTRIDE ((size_t)16384 * 320)
#define TSTRIDE ((size_t)16384 * 64)

// ---------- bf16 helpers ----------
__device__ inline ushort_t f2bf(float f) {
    union { float f; uint_t u; } x; x.f = f;
    uint_t r = x.u + 0x7fffu + ((x.u >> 16) & 1u);
    return (ushort_t)(r >> 16);
}
__device__ inline float bf2f(ushort_t h) {
    union { uint_t u; float f; } x; x.u = ((uint_t)h) << 16;
    return x.f;
}
__device__ inline float bflo(uint_t u) {
    union { uint_t u; float f; } x; x.u = u << 16; return x.f;
}
__device__ inline float bfhi(uint_t u) {
    union { uint_t u; float f; } x; x.u = u & 0xffff0000u; return x.f;
}
__device__ inline uint_t cvtpk_bf16(float lo, float hi) {
    uint_t r;
    asm volatile("v_cvt_pk_bf16_f32 %0, %1, %2" : "=v"(r) : "v"(lo), "v"(hi));
    return r;
}
__device__ inline void gload16(const void* g, void* l) {
    __builtin_amdgcn_global_load_lds(
        (const __attribute__((address_space(1))) void*)g,
        (__attribute__((address_space(3))) void*)l, 16, 0, 0);
}

// ---------- weight transform: OIHW fp32 -> [tap][co][ci] bf16 ----------
__global__ void wtrans_k(const float* __restrict__ w, ushort_t* __restrict__ wT, int CO, int CI)
{
    int idx = blockIdx.x * 256 + threadIdx.x;
    if (idx >= CO * CI * 9) return;
    int tap = idx % 9;
    int rem = idx / 9;
    int ci = rem % CI;
    int co = rem / CI;
    wT[((size_t)tap * CO + co) * CI + ci] = f2bf(w[idx]);
}

// ---------- conv0: 3->64 @128x128, NCHW fp32 in, NHWC bf16 out (batched) ----------
__global__ __launch_bounds__(256) void conv0_k(const float* __restrict__ x0, const float* __restrict__ x1,
                                               const float* __restrict__ w,
                                               const float* __restrict__ b, ushort_t* __restrict__ F)
{
    const float* x = blockIdx.y ? x1 : x0;
    F += (size_t)blockIdx.y * FSTRIDE;
    int co = threadIdx.x & 63;
    int p = blockIdx.x * 4 + (threadIdx.x >> 6);
    int y = p >> 7, xx = p & 127;
    float acc = b[co];
#pragma unroll
    for (int ci = 0; ci < 3; ++ci) {
#pragma unroll
        for (int t = 0; t < 9; ++t) {
            int dy = t / 3 - 1, dx = t % 3 - 1;
            int yy = y + dy, xc = xx + dx;
            if ((unsigned)yy < 128u && (unsigned)xc < 128u) {
                acc += x[ci * 16384 + yy * 128 + xc] * w[co * 27 + ci * 9 + t];
            }
        }
    }
    F[(size_t)p * 320 + co] = f2bf(fmaxf(acc, 0.f));
}

// ---------- implicit-GEMM MFMA conv 3x3 pad=1: NHWC bf16, relu (4-wave, batched) ----------
template<int CI>
__global__ __launch_bounds__(256) void conv_mfma_k(
    const ushort_t* __restrict__ in, int ldin, int inoff, size_t inImgStride,
    const ushort_t* __restrict__ wT, const float* __restrict__ bias,
    ushort_t* __restrict__ out, int ldout, int outoff, size_t outImgStride,
    int H, int W, int CO)
{
    in += (size_t)blockIdx.z * inImgStride;
    out += (size_t)blockIdx.z * outImgStride;
    const int tid = threadIdx.x;
    const int lane = tid & 63, wid = tid >> 6;
    const int wr = wid >> 1, wc = wid & 1;
    const int m0 = blockIdx.x * 64;
    const int n0 = blockIdx.y * 64;
    const int fr = lane & 15;
    const int fo = (lane >> 4) << 3;

    size_t abase[2];
    unsigned vmask[2];
#pragma unroll
    for (int mi = 0; mi < 2; ++mi) {
        int p = m0 + wr * 32 + mi * 16 + fr;
        int y = p / W, x = p % W;
        abase[mi] = (size_t)p * ldin + inoff + fo;
        unsigned vm = 0;
#pragma unroll
        for (int t = 0; t < 9; ++t) {
            int dy = t / 3 - 1, dx = t % 3 - 1;
            if ((unsigned)(y + dy) < (unsigned)H && (unsigned)(x + dx) < (unsigned)W) vm |= 1u << t;
        }
        vmask[mi] = vm;
    }

    f32x4 zero = {0.f, 0.f, 0.f, 0.f};
    f32x4 acc[2][2] = {{zero, zero}, {zero, zero}};
    const bf16x8 zz = {0, 0, 0, 0, 0, 0, 0, 0};

    for (int t = 0; t < 9; ++t) {
        int toff = ((t / 3 - 1) * W + (t % 3 - 1)) * ldin;
        bool v0 = (vmask[0] >> t) & 1u;
        bool v1 = (vmask[1] >> t) & 1u;
        const ushort_t* wp0 = wT + ((size_t)(t * CO + n0 + wc * 32 + fr)) * CI + fo;
        const ushort_t* wp1 = wp0 + (size_t)16 * CI;
#pragma unroll
        for (int kc = 0; kc < CI / 32; ++kc) {
            int k0 = kc * 32;
            bf16x8 a0 = v0 ? *(const bf16x8*)(in + abase[0] + toff + k0) : zz;
            bf16x8 a1 = v1 ? *(const bf16x8*)(in + abase[1] + toff + k0) : zz;
            bf16x8 b0 = *(const bf16x8*)(wp0 + k0);
            bf16x8 b1 = *(const bf16x8*)(wp1 + k0);
            // swapped operands: lane&15 -> pixel, reg group -> channel
            acc[0][0] = __builtin_amdgcn_mfma_f32_16x16x32_bf16(b0, a0, acc[0][0], 0, 0, 0);
            acc[0][1] = __builtin_amdgcn_mfma_f32_16x16x32_bf16(b1, a0, acc[0][1], 0, 0, 0);
            acc[1][0] = __builtin_amdgcn_mfma_f32_16x16x32_bf16(b0, a1, acc[1][0], 0, 0, 0);
            acc[1][1] = __builtin_amdgcn_mfma_f32_16x16x32_bf16(b1, a1, acc[1][1], 0, 0, 0);
        }
    }

#pragma unroll
    for (int mi = 0; mi < 2; ++mi) {
#pragma unroll
        for (int ni = 0; ni < 2; ++ni) {
            int pix = m0 + wr * 32 + mi * 16 + (lane & 15);
            int ch = n0 + wc * 32 + ni * 16 + ((lane >> 4) << 2);
            float4 bv = *(const float4*)(bias + ch);
            float r0 = fmaxf(acc[mi][ni][0] + bv.x, 0.f);
            float r1 = fmaxf(acc[mi][ni][1] + bv.y, 0.f);
            float r2 = fmaxf(acc[mi][ni][2] + bv.z, 0.f);
            float r3 = fmaxf(acc[mi][ni][3] + bv.w, 0.f);
            uint2 pk;
            pk.x = (uint_t)f2bf(r0) | ((uint_t)f2bf(r1) << 16);
            pk.y = (uint_t)f2bf(r2) | ((uint_t)f2bf(r3) << 16);
            *(uint2*)(out + (size_t)pix * ldout + outoff + ch) = pk;
        }
    }
}

// ---------- 1-wave variant (32x32 tile) for deep low-res layers ----------
template<int CI>
__global__ __launch_bounds__(64) void conv_mfma1w_k(
    const ushort_t* __restrict__ in, int ldin, size_t inImgStride,
    const ushort_t* __restrict__ wT, const float* __restrict__ bias,
    ushort_t* __restrict__ out, int ldout, size_t outImgStride,
    int H, int W, int CO)
{
    in += (size_t)blockIdx.z * inImgStride;
    out += (size_t)blockIdx.z * outImgStride;
    const int lane = threadIdx.x;
    const int m0 = blockIdx.x * 32;
    const int n0 = blockIdx.y * 32;
    const int fr = lane & 15;
    const int fo = (lane >> 4) << 3;

    size_t abase[2];
    unsigned vmask[2];
#pragma unroll
    for (int mi = 0; mi < 2; ++mi) {
        int p = m0 + mi * 16 + fr;
        int y = p / W, x = p % W;
        abase[mi] = (size_t)p * ldin + fo;
        unsigned vm = 0;
#pragma unroll
        for (int t = 0; t < 9; ++t) {
            int dy = t / 3 - 1, dx = t % 3 - 1;
            if ((unsigned)(y + dy) < (unsigned)H && (unsigned)(x + dx) < (unsigned)W) vm |= 1u << t;
        }
        vmask[mi] = vm;
    }

    f32x4 zero = {0.f, 0.f, 0.f, 0.f};
    f32x4 acc[2][2] = {{zero, zero}, {zero, zero}};
    const bf16x8 zz = {0, 0, 0, 0, 0, 0, 0, 0};

    for (int t = 0; t < 9; ++t) {
        int toff = ((t / 3 - 1) * W + (t % 3 - 1)) * ldin;
        bool v0 = (vmask[0] >> t) & 1u;
        bool v1 = (vmask[1] >> t) & 1u;
        const ushort_t* wp0 = wT + ((size_t)(t * CO + n0 + fr)) * CI + fo;
        const ushort_t* wp1 = wp0 + (size_t)16 * CI;
#pragma unroll
        for (int kc = 0; kc < CI / 32; ++kc) {
            int k0 = kc * 32;
            bf16x8 a0 = v0 ? *(const bf16x8*)(in + abase[0] + toff + k0) : zz;
            bf16x8 a1 = v1 ? *(const bf16x8*)(in + abase[1] + toff + k0) : zz;
            bf16x8 b0 = *(const bf16x8*)(wp0 + k0);
            bf16x8 b1 = *(const bf16x8*)(wp1 + k0);
            acc[0][0] = __builtin_amdgcn_mfma_f32_16x16x32_bf16(b0, a0, acc[0][0], 0, 0, 0);
            acc[0][1] = __builtin_amdgcn_mfma_f32_16x16x32_bf16(b1, a0, acc[0][1], 0, 0, 0);
            acc[1][0] = __builtin_amdgcn_mfma_f32_16x16x32_bf16(b0, a1, acc[1][0], 0, 0, 0);
            acc[1][1] = __builtin_amdgcn_mfma_f32_16x16x32_bf16(b1, a1, acc[1][1], 0, 0, 0);
        }
    }

#pragma unroll
    for (int mi = 0; mi < 2; ++mi) {
#pragma unroll
        for (int ni = 0; ni < 2; ++ni) {
            int pix = m0 + mi * 16 + (lane & 15);
            int ch = n0 + ni * 16 + ((lane >> 4) << 2);
            float4 bv = *(const float4*)(bias + ch);
            float r0 = fmaxf(acc[mi][ni][0] + bv.x, 0.f);
            float r1 = fmaxf(acc[mi][ni][1] + bv.y, 0.f);
            float r2 = fmaxf(acc[mi][ni][2] + bv.z, 0.f);
            float r3 = fmaxf(acc[mi][ni][3] + bv.w, 0.f);
            uint2 pk;
            pk.x = (uint_t)f2bf(r0) | ((uint_t)f2bf(r1) << 16);
            pk.y = (uint_t)f2bf(r2) | ((uint_t)f2bf(r3) << 16);
            *(uint2*)(out + (size_t)pix * ldout + ch) = pk;
        }
    }
}

// ---------- 2x2 maxpool NHWC bf16 (batched via blockIdx.y) ----------
__global__ void maxpool_nhwc_k(const ushort_t* __restrict__ in, ushort_t* __restrict__ out,
                               int C, int Hi, int Wi)
{
    in += (size_t)blockIdx.y * TSTRIDE;
    out += (size_t)blockIdx.y * TSTRIDE;
    int idx = blockIdx.x * 256 + threadIdx.x;
    int CG = C >> 3;
    int Wo = Wi >> 1, Ho = Hi >> 1;
    if (idx >= Ho * Wo * CG) return;
    int cg = idx % CG;
    int p = idx / CG;
    int y = p / Wo, x = p % Wo;
    const ushort_t* ip = in + ((size_t)(2 * y) * Wi + 2 * x) * C + cg * 8;
    bf16x8 v0 = *(const bf16x8*)(ip);
    bf16x8 v1 = *(const bf16x8*)(ip + C);
    bf16x8 v2 = *(const bf16x8*)(ip + (size_t)Wi * C);
    bf16x8 v3 = *(const bf16x8*)(ip + (size_t)Wi * C + C);
    bf16x8 r;
#pragma unroll
    for (int j = 0; j < 8; ++j) {
        float m = fmaxf(fmaxf(bf2f((ushort_t)v0[j]), bf2f((ushort_t)v1[j])),
                        fmaxf(bf2f((ushort_t)v2[j]), bf2f((ushort_t)v3[j])));
        r[j] = (short)f2bf(m);
    }
    *(bf16x8*)(out + (size_t)p * C + cg * 8) = r;
}

// ---------- bicubic weights (align_corners=True), PyTorch A=-0.75 ----------
__device__ inline void cubw(float t, float* w) {
    float x0 = 1.f + t, x2 = 1.f - t, x3 = 2.f - t;
    w[0] = ((-0.75f*x0 + 3.75f)*x0 - 6.f)*x0 + 3.f;
    w[1] = (1.25f*t - 2.25f)*t*t + 1.f;
    w[2] = (1.25f*x2 - 2.25f)*x2*x2 + 1.f;
    w[3] = ((-0.75f*x3 + 3.75f)*x3 - 6.f)*x3 + 3.f;
}

// ---------- bicubic 32->128 NHWC bf16 (256 ch) into F cols 64..319 (batched) ----------
__global__ __launch_bounds__(256) void bicubic_nhwc_k(const ushort_t* __restrict__ in, ushort_t* __restrict__ F)
{
    in += (size_t)blockIdx.y * TSTRIDE;
    F += (size_t)blockIdx.y * FSTRIDE;
    int idx = blockIdx.x * 256 + threadIdx.x;
    int cg = idx & 31;
    int p = idx >> 5;
    int Y = p >> 7, X = p & 127;
    float sy = (float)Y * (31.f / 127.f);
    float sx = (float)X * (31.f / 127.f);
    int fy = (int)floorf(sy), fx = (int)floorf(sx);
    float ty = sy - (float)fy, tx = sx - (float)fx;
    float wy[4], wx[4];
    cubw(ty, wy); cubw(tx, wx);
    float a[8] = {0.f, 0.f, 0.f, 0.f, 0.f, 0.f, 0.f, 0.f};
#pragma unroll
    for (int i = 0; i < 4; ++i) {
        int yy = min(max(fy - 1 + i, 0), 31);
#pragma unroll
        for (int j = 0; j < 4; ++j) {
            int xx = min(max(fx - 1 + j, 0), 31);
            float w = wy[i] * wx[j];
            bf16x8 v = *(const bf16x8*)(in + ((size_t)yy * 32 + xx) * 256 + cg * 8);
#pragma unroll
            for (int e = 0; e < 8; ++e) a[e] += w * bf2f((ushort_t)v[e]);
        }
    }
    bf16x8 r;
#pragma unroll
    for (int e = 0; e < 8; ++e) r[e] = (short)f2bf(a[e]);
    *(bf16x8*)(F + (size_t)p * 320 + 64 + cg * 8) = r;
}

// ---------- in-place L2-normalize rows of F [2*16384][320] bf16 (wave per pixel) ----------
__global__ __launch_bounds__(256) void norm_k(ushort_t* __restrict__ F)
{
    int lane = threadIdx.x & 63;
    int p = blockIdx.x * 4 + (threadIdx.x >> 6);
    ushort_t* rp = F + (size_t)p * 320;
    bool act = lane < 40;
    bf16x8 v = {0, 0, 0, 0, 0, 0, 0, 0};
    float ss = 0.f;
    if (act) {
        v = *(const bf16x8*)(rp + lane * 8);
#pragma unroll
        for (int e = 0; e < 8; ++e) { float f = bf2f((ushort_t)v[e]); ss += f * f; }
    }
#pragma unroll
    for (int off = 32; off > 0; off >>= 1) ss += __shfl_xor(ss, off);
    float inv = 1.f / (1e-8f + sqrtf(ss));
    if (act) {
#pragma unroll
        for (int e = 0; e < 8; ++e) v[e] = (short)f2bf(bf2f((ushort_t)v[e]) * inv);
        *(bf16x8*)(rp + lane * 8) = v;
    }
}

// ---------- 2x2 mean pool on normalized F_ref -> Abuf [4096][320] bf16 ----------
__global__ void pool_ref_nhwc_k(const ushort_t* __restrict__ F, ushort_t* __restrict__ A)
{
    int idx = blockIdx.x * 256 + threadIdx.x;
    if (idx >= 4096 * 40) return;
    int cg = idx % 40;
    int m = idx / 40;
    int y = m >> 6, x = m & 63;
    const ushort_t* ip = F + ((size_t)(2 * y) * 128 + 2 * x) * 320 + cg * 8;
    bf16x8 v0 = *(const bf16x8*)(ip);
    bf16x8 v1 = *(const bf16x8*)(ip + 320);
    bf16x8 v2 = *(const bf16x8*)(ip + 128 * 320);
    bf16x8 v3 = *(const bf16x8*)(ip + 128 * 320 + 320);
    bf16x8 r;
#pragma unroll
    for (int j = 0; j < 8; ++j) {
        float s = bf2f((ushort_t)v0[j]) + bf2f((ushort_t)v1[j]) + bf2f((ushort_t)v2[j]) + bf2f((ushort_t)v3[j]);
        r[j] = (short)f2bf(0.25f * s);
    }
    *(bf16x8*)(A + (size_t)m * 320 + cg * 8) = r;
}

// ---------- correlation GEMM + fused softmax-denominator partials ----------
// A[4096][320] x B[16384][320]^T -> dist bf16 [4096][16384] (scaled 1/320)
// global_load_lds staging; swapped-operand MFMA for packed 8B stores.
__global__ __launch_bounds__(256) void gemm_corr_k(
    const ushort_t* __restrict__ A, const ushort_t* __restrict__ B, ushort_t* __restrict__ D,
    const float* __restrict__ coefr, const float* __restrict__ coeft,
    float* __restrict__ rpsum, float* __restrict__ cpsum)
{
    __shared__ ushort_t lA[128 * 32];
    __shared__ ushort_t lB[128 * 32];
    __shared__ float cl[2][128];
    __shared__ float rl[2][128];
    const int tid = threadIdx.x;
    const int lane = tid & 63;
    const int wid = tid >> 6;
    const int wr = wid >> 1, wc = wid & 1;
    const int m0 = blockIdx.y * 128, n0 = blockIdx.x * 128;
    const int fr = lane & 15;
    const int fo = (lane >> 4) << 3;
    const int srow = tid >> 2;
    const int scol = (tid & 3) << 3;

    const ushort_t* Ag0 = A + (size_t)(m0 + srow) * 320 + scol;
    const ushort_t* Ag1 = Ag0 + (size_t)64 * 320;
    const ushort_t* Bg0 = B + (size_t)(n0 + srow) * 320 + scol;
    const ushort_t* Bg1 = Bg0 + (size_t)64 * 320;
    ushort_t* lA0 = lA + wid * 512;
    ushort_t* lA1 = lA + 2048 + wid * 512;
    ushort_t* lB0 = lB + wid * 512;
    ushort_t* lB1 = lB + 2048 + wid * 512;

    f32x4 zero = {0.f, 0.f, 0.f, 0.f};
    f32x4 acc[4][4];
#pragma unroll
    for (int i = 0; i < 4; ++i)
#pragma unroll
        for (int j = 0; j < 4; ++j) acc[i][j] = zero;

    for (int k0 = 0; k0 < 320; k0 += 32) {
        gload16(Ag0 + k0, lA0);
        gload16(Ag1 + k0, lA1);
        gload16(Bg0 + k0, lB0);
        gload16(Bg1 + k0, lB1);
        __syncthreads();   // drains vmcnt -> LDS valid
        bf16x8 af[4], bfr[4];
#pragma unroll
        for (int mi = 0; mi < 4; ++mi)
            af[mi] = *(const bf16x8*)&lA[(wr * 64 + mi * 16 + fr) * 32 + fo];
#pragma unroll
        for (int ni = 0; ni < 4; ++ni)
            bfr[ni] = *(const bf16x8*)&lB[(wc * 64 + ni * 16 + fr) * 32 + fo];
#pragma unroll
        for (int mi = 0; mi < 4; ++mi)
#pragma unroll
            for (int ni = 0; ni < 4; ++ni)   // swapped: lane&15 -> m, reg group -> n
                acc[mi][ni] = __builtin_amdgcn_mfma_f32_16x16x32_bf16(bfr[ni], af[mi], acc[mi][ni], 0, 0, 0);
        __syncthreads();   // all reads done before next stage
    }

    const float s = 1.0f / 320.0f;
    const float cr = coefr[0], ct = coeft[0];
    const bool sameCoef = (cr == ct);
    float rpx[4] = {0.f, 0.f, 0.f, 0.f};
    float cpx[4][4];
#pragma unroll
    for (int ni = 0; ni < 4; ++ni)
#pragma unroll
        for (int r = 0; r < 4; ++r) cpx[ni][r] = 0.f;

    const int mrow = lane & 15;
    const int ng = (lane >> 4) << 2;
#pragma unroll
    for (int mi = 0; mi < 4; ++mi) {
        int m = m0 + wr * 64 + mi * 16 + mrow;
        ushort_t* drow = D + (size_t)m * 16384;
#pragma unroll
        for (int ni = 0; ni < 4; ++ni) {
            int n = n0 + wc * 64 + ni * 16 + ng;
            float d0 = acc[mi][ni][0] * s;
            float d1 = acc[mi][ni][1] * s;
            float d2 = acc[mi][ni][2] * s;
            float d3 = acc[mi][ni][3] * s;
            uint2 pk;
            pk.x = cvtpk_bf16(d0, d1);
            pk.y = cvtpk_bf16(d2, d3);
            *(uint2*)(drow + n) = pk;
            float e0 = __expf(cr * d0), e1 = __expf(cr * d1);
            float e2 = __expf(cr * d2), e3 = __expf(cr * d3);
            cpx[ni][0] += e0; cpx[ni][1] += e1; cpx[ni][2] += e2; cpx[ni][3] += e3;
            if (sameCoef) {
                rpx[mi] += e0 + e1 + e2 + e3;
            } else {
                rpx[mi] += __expf(ct * d0) + __expf(ct * d1) + __expf(ct * d2) + __expf(ct * d3);
            }
        }
    }
    // row partials: reduce over n-groups (lane>>4)
#pragma unroll
    for (int mi = 0; mi < 4; ++mi) {
        rpx[mi] += __shfl_xor(rpx[mi], 16);
        rpx[mi] += __shfl_xor(rpx[mi], 32);
    }
    if (lane < 16) {
#pragma unroll
        for (int mi = 0; mi < 4; ++mi)
            rl[wc][wr * 64 + mi * 16 + lane] = rpx[mi];
    }
    // col partials: reduce over m-rows (lane&15)
#pragma unroll
    for (int ni = 0; ni < 4; ++ni)
#pragma unroll
        for (int r = 0; r < 4; ++r) {
            cpx[ni][r] += __shfl_xor(cpx[ni][r], 1);
            cpx[ni][r] += __shfl_xor(cpx[ni][r], 2);
            cpx[ni][r] += __shfl_xor(cpx[ni][r], 4);
            cpx[ni][r] += __shfl_xor(cpx[ni][r], 8);
        }
    if ((lane & 15) == 0) {
        int g = lane >> 4;
#pragma unroll
        for (int ni = 0; ni < 4; ++ni)
#pragma unroll
            for (int r = 0; r < 4; ++r)
                cl[wr][wc * 64 + ni * 16 + g * 4 + r] = cpx[ni][r];
    }
    __syncthreads();
    if (tid < 128) {
        cpsum[(size_t)blockIdx.y * 16384 + n0 + tid] = cl[0][tid] + cl[1][tid];
        rpsum[(size_t)blockIdx.x * 4096 + m0 + tid] = rl[0][tid] + rl[1][tid];
    }
}

// ---------- finalize: lc[j] = -0.5*log(colsum), invr[m] = rsqrt(rowsum) ----------
__global__ void colfin_k(const float* __restrict__ cpsum, float* __restrict__ lc)
{
    int j = blockIdx.x * 256 + threadIdx.x;
    float s = 0.f;
#pragma unroll
    for (int k = 0; k < 32; ++k) s += cpsum[(size_t)k * 16384 + j];
    lc[j] = -0.5f * __logf(s);
}
__global__ void rowfin_k(const float* __restrict__ rpsum, float* __restrict__ invr)
{
    int m = blockIdx.x * 256 + threadIdx.x;
    float s = 0.f;
#pragma unroll
    for (int k = 0; k < 128; ++k) s += rpsum[(size_t)k * 4096 + m];
    invr[m] = rsqrtf(s);
}

// ---------- per-row top-5 in key space: key = hc*d + lc[j] (one wave per row) ----------
#define INS5(w_) { float w = (w_); float mx; \
    mx = fmaxf(w, t0); w = fminf(w, t0); t0 = mx; \
    mx = fmaxf(w, t1); w = fminf(w, t1); t1 = mx; \
    mx = fmaxf(w, t2); w = fminf(w, t2); t2 = mx; \
    mx = fmaxf(w, t3); w = fminf(w, t3); t3 = mx; \
    t4 = fmaxf(w, t4); }

__global__ __launch_bounds__(256) void row_topk_k(
    const ushort_t* __restrict__ Dist, const float* __restrict__ lc,
    const float* __restrict__ invr,
    const float* __restrict__ coefr, const float* __restrict__ coeft,
    float* __restrict__ conf5)
{
    int wid = threadIdx.x >> 6, lane = threadIdx.x & 63;
    int row = blockIdx.x * 4 + wid;
    float hc = 0.5f * (coefr[0] + coeft[0]);
    const ushort_t* rp = Dist + (size_t)row * 16384;

    float t0 = -1e30f, t1 = -1e30f, t2 = -1e30f, t3 = -1e30f, t4 = -1e30f;
    for (int i = 0; i < 32; ++i) {
        int col = (i * 64 + lane) * 8;
        uint4 u = *(const uint4*)(rp + col);
        float4 l0 = *(const float4*)(lc + col);
        float4 l1 = *(const float4*)(lc + col + 4);
        INS5(fmaf(hc, bflo(u.x), l0.x));
        INS5(fmaf(hc, bfhi(u.x), l0.y));
        INS5(fmaf(hc, bflo(u.y), l0.z));
        INS5(fmaf(hc, bfhi(u.y), l0.w));
        INS5(fmaf(hc, bflo(u.z), l1.x));
        INS5(fmaf(hc, bfhi(u.z), l1.y));
        INS5(fmaf(hc, bflo(u.w), l1.z));
        INS5(fmaf(hc, bfhi(u.w), l1.w));
    }
#pragma unroll
    for (int off = 1; off < 64; off <<= 1) {
        float o0 = __shfl_xor(t0, off), o1 = __shfl_xor(t1, off), o2 = __shfl_xor(t2, off);
        float o3 = __shfl_xor(t3, off), o4 = __shfl_xor(t4, off);
        INS5(o0); INS5(o1); INS5(o2); INS5(o3); INS5(o4);
    }
    if (lane == 0) {
        float iv = invr[row];
        conf5[0 * 4096 + row] = __expf(t0) * iv;
        conf5[1 * 4096 + row] = __expf(t1) * iv;
        conf5[2 * 4096 + row] = __expf(t2) * iv;
        conf5[3 * 4096 + row] = __expf(t3) * iv;
        conf5[4 * 4096 + row] = __expf(t4) * iv;
    }
}

// ---------- fp32 3x3 conv (head only, NCHW) ----------
__global__ void conv3x3_k(const float* __restrict__ in, const float* __restrict__ wgt,
                          const float* __restrict__ bias, float* __restrict__ out,
                          int Cin, int H, int W, int relu)
{
    int p = blockIdx.x * 256 + threadIdx.x;
    int HW = H * W;
    if (p >= HW) return;
    int co0 = blockIdx.y * 8;
    int y = p / W, x = p - y * W;
    float acc0 = bias[co0+0], acc1 = bias[co0+1], acc2 = bias[co0+2], acc3 = bias[co0+3];
    float acc4 = bias[co0+4], acc5 = bias[co0+5], acc6 = bias[co0+6], acc7 = bias[co0+7];
    bool ym = y > 0, yp = y < H-1, xm = x > 0, xp = x < W-1;
    for (int ci = 0; ci < Cin; ++ci) {
        const float* ip = in + (size_t)ci * HW + p;
        float v0 = (ym && xm) ? ip[-W-1] : 0.f;
        float v1 = (ym)       ? ip[-W]   : 0.f;
        float v2 = (ym && xp) ? ip[-W+1] : 0.f;
        float v3 = (xm)       ? ip[-1]   : 0.f;
        float v4 =              ip[0];
        float v5 = (xp)       ? ip[1]    : 0.f;
        float v6 = (yp && xm) ? ip[W-1]  : 0.f;
        float v7 = (yp)       ? ip[W]    : 0.f;
        float v8 = (yp && xp) ? ip[W+1]  : 0.f;
        const float* wp = wgt + ((size_t)co0 * Cin + ci) * 9;
        size_t ws = (size_t)Cin * 9;
#define CACC(q, a) { const float* wq = wp + q * ws; \
        a += wq[0]*v0 + wq[1]*v1 + wq[2]*v2 + wq[3]*v3 + wq[4]*v4 \
           + wq[5]*v5 + wq[6]*v6 + wq[7]*v7 + wq[8]*v8; }
        CACC(0, acc0) CACC(1, acc1) CACC(2, acc2) CACC(3, acc3)
        CACC(4, acc4) CACC(5, acc5) CACC(6, acc6) CACC(7, acc7)
#undef CACC
    }
#define CW(q, a) { float r = a; if (relu) r = fmaxf(r, 0.f); out[(size_t)(co0+q)*HW + p] = r; }
    CW(0, acc0) CW(1, acc1) CW(2, acc2) CW(3, acc3)
    CW(4, acc4) CW(5, acc5) CW(6, acc6) CW(7, acc7)
#undef CW
}

// ---------- fp32 bicubic (final output) ----------
__global__ void bicubic_k(const float* __restrict__ in, float* __restrict__ out,
                          int C, int Hin, int Win, int Hout, int Wout)
{
    int idx = blockIdx.x * 256 + threadIdx.x;
    int total = C * Hout * Wout;
    if (idx >= total) return;
    int X = idx % Wout;
    int Y = (idx / Wout) % Hout;
    int c = idx / (Wout * Hout);
    float sy = (float)Y * (float)(Hin - 1) / (float)(Hout - 1);
    float sx = (float)X * (float)(Win - 1) / (float)(Wout - 1);
    int fy = (int)floorf(sy), fx = (int)floorf(sx);
    float ty = sy - (float)fy, tx = sx - (float)fx;
    float wy[4], wx[4];
    cubw(ty, wy); cubw(tx, wx);
    const float* ip = in + (size_t)c * Hin * Win;
    float acc = 0.f;
#pragma unroll
    for (int i = 0; i < 4; ++i) {
        int yy = min(max(fy - 1 + i, 0), Hin - 1);
        float ra = 0.f;
#pragma unroll
        for (int j = 0; j < 4; ++j) {
            int xx = min(max(fx - 1 + j, 0), Win - 1);
            ra += wx[j] * ip[yy * Win + xx];
        }
        acc += wy[i] * ra;
    }
    out[idx] = acc;
}

// ---------- 1x1 conv, Cin->1 ----------
__global__ void conv1x1_k(const float* __restrict__ in, const float* __restrict__ w,
                          const float* __restrict__ b, float* __restrict__ out, int Cin, int HW)
{
    int p = blockIdx.x * 256 + threadIdx.x;
    if (p >= HW) return;
    float a = b[0];
    for (int c = 0; c < Cin; ++c) a += w[c] * in[(size_t)c * HW + p];
    out[p] = a;
}

// ---------- host ----------
extern "C" void kernel_launch(void* const* d_in, const int* in_sizes, int n_in,
                              void* d_out, int out_size, void* d_ws, size_t ws_size,
                              hipStream_t stream)
{
    const float* x_ref = (const float*)d_in[0];
    const float* x_tem = (const float*)d_in[1];
    const float* w0  = (const float*)d_in[2];   const float* b0  = (const float*)d_in[3];
    const float* w2  = (const float*)d_in[4];   const float* b2  = (const float*)d_in[5];
    const float* w5  = (const float*)d_in[6];   const float* b5  = (const float*)d_in[7];
    const float* w7  = (const float*)d_in[8];   const float* b7  = (const float*)d_in[9];
    const float* w10 = (const float*)d_in[10];  const float* b10 = (const float*)d_in[11];
    const float* w12 = (const float*)d_in[12];  const float* b12 = (const float*)d_in[13];
    const float* w14 = (const float*)d_in[14];  const float* b14 = (const float*)d_in[15];
    const float* coefr = (const float*)d_in[16];
    const float* coeft = (const float*)d_in[17];
    const float* fw1 = (const float*)d_in[18];  const float* fb1 = (const float*)d_in[19];
    const float* fw2 = (const float*)d_in[20];  const float* fb2 = (const float*)d_in[21];
    const float* fw3 = (const float*)d_in[22];  const float* fb3 = (const float*)d_in[23];
    float* out = (float*)d_out;

    char* wsp = (char*)d_ws;
    auto alloc = [&](size_t bytes) { char* p = wsp; wsp += (bytes + 255) & ~(size_t)255; return p; };
    ushort_t* F     = (ushort_t*)alloc(2 * FSTRIDE * 2);   // [2][16384][320]
    ushort_t* t1    = (ushort_t*)alloc(2 * TSTRIDE * 2);
    ushort_t* t2    = (ushort_t*)alloc(2 * TSTRIDE * 2);
    ushort_t* wT2   = (ushort_t*)alloc((size_t)64 * 64 * 9 * 2);
    ushort_t* wT5   = (ushort_t*)alloc((size_t)128 * 64 * 9 * 2);
    ushort_t* wT7   = (ushort_t*)alloc((size_t)128 * 128 * 9 * 2);
    ushort_t* wT10  = (ushort_t*)alloc((size_t)256 * 128 * 9 * 2);
    ushort_t* wT12  = (ushort_t*)alloc((size_t)256 * 256 * 9 * 2);
    ushort_t* wT14  = (ushort_t*)alloc((size_t)256 * 256 * 9 * 2);
    ushort_t* Abuf  = (ushort_t*)alloc((size_t)4096 * 320 * 2);
    ushort_t* dist  = (ushort_t*)alloc((size_t)4096 * 16384 * 2);
    float*    rpsum = (float*)alloc((size_t)128 * 4096 * 4);
    float*    cpsum = (float*)alloc((size_t)32 * 16384 * 4);
    float*    lc    = (float*)alloc(16384 * 4);
    float*    invr  = (float*)alloc(4096 * 4);
    float*    conf5 = (float*)alloc(5 * 4096 * 4);
    float*    h1    = (float*)alloc(8 * 4096 * 4);
    float*    h2    = (float*)alloc(8 * 4096 * 4);
    float*    out64 = (float*)alloc(4096 * 4);
    (void)ws_size; (void)n_in; (void)in_sizes; (void)out_size;

    // weight transforms (tiny)
    wtrans_k<<<(64*64*9 + 255)/256, 256, 0, stream>>>(w2, wT2, 64, 64);
    wtrans_k<<<(128*64*9 + 255)/256, 256, 0, stream>>>(w5, wT5, 128, 64);
    wtrans_k<<<(128*128*9 + 255)/256, 256, 0, stream>>>(w7, wT7, 128, 128);
    wtrans_k<<<(256*128*9 + 255)/256, 256, 0, stream>>>(w10, wT10, 256, 128);
    wtrans_k<<<(256*256*9 + 255)/256, 256, 0, stream>>>(w12, wT12, 256, 256);
    wtrans_k<<<(256*256*9 + 255)/256, 256, 0, stream>>>(w14, wT14, 256, 256);

    // batched feature extraction (img 0 = ref, img 1 = template)
    conv0_k<<<dim3(4096, 2), 256, 0, stream>>>(x_ref, x_tem, w0, b0, F);
    conv_mfma_k<64><<<dim3(256, 1, 2), 256, 0, stream>>>(F, 320, 0, FSTRIDE, wT2, b2, t1, 64, 0, TSTRIDE, 128, 128, 64);
    maxpool_nhwc_k<<<dim3(128, 2), 256, 0, stream>>>(t1, t2, 64, 128, 128);
    conv_mfma_k<64><<<dim3(64, 2, 2), 256, 0, stream>>>(t2, 64, 0, TSTRIDE, wT5, b5, t1, 128, 0, TSTRIDE, 64, 64, 128);
    conv_mfma_k<128><<<dim3(64, 2, 2), 256, 0, stream>>>(t1, 128, 0, TSTRIDE, wT7, b7, t2, 128, 0, TSTRIDE, 64, 64, 128);
    maxpool_nhwc_k<<<dim3(64, 2), 256, 0, stream>>>(t2, t1, 128, 64, 64);
    conv_mfma1w_k<128><<<dim3(32, 8, 2), 64, 0, stream>>>(t1, 128, TSTRIDE, wT10, b10, t2, 256, TSTRIDE, 32, 32, 256);
    conv_mfma1w_k<256><<<dim3(32, 8, 2), 64, 0, stream>>>(t2, 256, TSTRIDE, wT12, b12, t1, 256, TSTRIDE, 32, 32, 256);
    conv_mfma1w_k<256><<<dim3(32, 8, 2), 64, 0, stream>>>(t1, 256, TSTRIDE, wT14, b14, t2, 256, TSTRIDE, 32, 32, 256);
    bicubic_nhwc_k<<<dim3(2048, 2), 256, 0, stream>>>(t2, F);
    norm_k<<<8192, 256, 0, stream>>>(F);

    pool_ref_nhwc_k<<<640, 256, 0, stream>>>(F, Abuf);

    // correlation GEMM with fused softmax-denominator partials
    gemm_corr_k<<<dim3(128, 32), 256, 0, stream>>>(Abuf, F + FSTRIDE, dist, coefr, coeft, rpsum, cpsum);

    colfin_k<<<64, 256, 0, stream>>>(cpsum, lc);
    rowfin_k<<<16, 256, 0, stream>>>(rpsum, invr);

    // fused key-space top-5
    row_topk_k<<<1024, 256, 0, stream>>>(dist, lc, invr, coefr, coeft, conf5);

    conv3x3_k<<<dim3(16, 1), 256, 0, stream>>>(conf5, fw1, fb1, h1, 5, 64, 64, 1);
    conv3x3_k<<<dim3(16, 1), 256, 0, stream>>>(h1, fw2, fb2, h2, 8, 64, 64, 1);
    conv1x1_k<<<16, 256, 0, stream>>>(h2, fw3, fb3, out64, 8, 4096);
    bicubic_k<<<64, 256, 0, stream>>>(out64, out, 1, 64, 64, 128, 128);
}